// Round 2
// baseline (914.945 us; speedup 1.0000x reference)
//
#include <hip/hip_runtime.h>
#include <math.h>

// Problem constants (fixed by setup_inputs)
#define BB 128
#define LFULL 257
#define LW 256     // L-1 words
#define TT 1024    // video frames
#define CC 256     // hidden
#define NH 8
#define DHD 32
#define PP 8       // NUM_PHRASE
#define NLAY 3

typedef __bf16 bf16x8 __attribute__((ext_vector_type(8)));
typedef __bf16 bf16x4 __attribute__((ext_vector_type(4)));
typedef float  f32x4  __attribute__((ext_vector_type(4)));

// ---------------- block reduce helpers (blockDim == 256 -> 4 waves) -------------
__device__ __forceinline__ float blockReduceSum(float v, volatile float* lds) {
#pragma unroll
    for (int m = 32; m >= 1; m >>= 1) v += __shfl_xor(v, m);
    __syncthreads();
    if ((threadIdx.x & 63) == 0) lds[threadIdx.x >> 6] = v;
    __syncthreads();
    return lds[0] + lds[1] + lds[2] + lds[3];
}
__device__ __forceinline__ float blockReduceMax(float v, volatile float* lds) {
#pragma unroll
    for (int m = 32; m >= 1; m >>= 1) v = fmaxf(v, __shfl_xor(v, m));
    __syncthreads();
    if ((threadIdx.x & 63) == 0) lds[threadIdx.x >> 6] = v;
    __syncthreads();
    return fmaxf(fmaxf(lds[0], lds[1]), fmaxf(lds[2], lds[3]));
}

// =================================================================================
// MFMA GEMM: C = A @ B^T (+bias).  A: M x K row-major bf16 (hi[,lo]).
// B: N x K row-major, either bf16 hi[,lo] (B_F32=0) or fp32 split in-kernel (B_F32=1).
// SPLIT=1: split-bf16 product (3 MFMAs) ~ fp32 accuracy. OUT_SPLIT=1: bf16 hi/lo out.
// 128x128 tile, BK=32, 256 threads (4 waves, 64x64 per wave, 4x4 16x16x32 frags).
//
// LDS uses a FRAGMENT-ORDERED layout (round-2 change): per 64-row half, 16 blocks
// of 256B indexed [(row>>4)&3][col>>3], inner [row&15][col&7]. A wave's fragment
// read fah[i] is then byte offset base + i*1024 + lane*16 -> linear in lane ->
// ZERO bank conflicts (old row-major LP=40 layout had 8-way conflicted reads and
// scalar even-bank-only staging stores in the fp32-split path: 8.4M conflicts,
// MfmaUtil 18.7%). Also 32KB LDS vs 40KB -> 5 blocks/CU.
// =================================================================================

__device__ __forceinline__ int ldsoff(int row, int col) {
    // row 0..127, col 0..31, returns bf16-element offset into a 4096-elem buffer
    return ((row >> 6) << 11)
         + ((((row >> 4) & 3) << 2) + (col >> 3)) * 128
         + ((row & 15) << 3) + (col & 7);
}

template<int SPLIT, int B_F32, int OUT_SPLIT>
__global__ __launch_bounds__(256) void gemm_mfma(
    const __bf16* __restrict__ Ahi, const __bf16* __restrict__ Alo, int lda, long long sA,
    const void* __restrict__ Bhp, const void* __restrict__ Blp, int ldb, long long sB,
    const float* __restrict__ bias,
    float* __restrict__ Cf, __bf16* __restrict__ Chi, __bf16* __restrict__ Clo,
    int ldc, long long sC, int M, int N, int K)
{
    __shared__ __bf16 sAh[4096];
    __shared__ __bf16 sAl[SPLIT ? 4096 : 1];
    __shared__ __bf16 sBh[4096];
    __shared__ __bf16 sBl[SPLIT ? 4096 : 1];

    const int tid = threadIdx.x;
    const int n0 = blockIdx.x * 128;
    const int m0 = blockIdx.y * 128;
    const long long bz = blockIdx.z;
    const __bf16* Ah = Ahi + bz * sA;
    const __bf16* Al = SPLIT ? (Alo + bz * sA) : nullptr;

    const int wv = tid >> 6, lane = tid & 63;
    const int wm = (wv & 1) << 6, wn = (wv >> 1) << 6;
    const int lr = lane & 15, quad = lane >> 4;

    const int sr = tid >> 2;          // 0..63
    const int sc = (tid & 3) << 3;    // 0,8,16,24
    const int fr = tid >> 3;          // 0..31
    const int fc = (tid & 7) << 2;    // 0..28

    // fragment-read bases (bf16 elems): linear in lane -> conflict-free b128 reads
    const int abase = ((wm >> 6) << 11) + (lane << 3);
    const int bbase = ((wn >> 6) << 11) + (lane << 3);

    f32x4 acc[4][4];
#pragma unroll
    for (int i = 0; i < 4; ++i)
#pragma unroll
        for (int j = 0; j < 4; ++j) acc[i][j] = (f32x4)(0.f);

    for (int k0 = 0; k0 < K; k0 += 32) {
        // ---- stage A (bf16 hi[,lo]) ----
#pragma unroll
        for (int j = 0; j < 2; ++j) {
            int row = sr + 64 * j;
            int off = ldsoff(row, sc);
            *(bf16x8*)&sAh[off] =
                *(const bf16x8*)&Ah[(long long)(m0 + row) * lda + k0 + sc];
            if constexpr (SPLIT)
                *(bf16x8*)&sAl[off] =
                    *(const bf16x8*)&Al[(long long)(m0 + row) * lda + k0 + sc];
        }
        // ---- stage B ----
        if constexpr (B_F32) {
            const float* Bf = (const float*)Bhp + bz * sB;
#pragma unroll
            for (int j = 0; j < 4; ++j) {
                int row = fr + 32 * j;
                float4 f = *(const float4*)&Bf[(long long)(n0 + row) * ldb + k0 + fc];
                bf16x4 h4, l4;
                h4[0] = (__bf16)f.x; l4[0] = (__bf16)(f.x - (float)h4[0]);
                h4[1] = (__bf16)f.y; l4[1] = (__bf16)(f.y - (float)h4[1]);
                h4[2] = (__bf16)f.z; l4[2] = (__bf16)(f.z - (float)h4[2]);
                h4[3] = (__bf16)f.w; l4[3] = (__bf16)(f.w - (float)h4[3]);
                int off = ldsoff(row, fc);
                *(bf16x4*)&sBh[off] = h4;
                *(bf16x4*)&sBl[off] = l4;
            }
        } else {
            const __bf16* Bh = (const __bf16*)Bhp + bz * sB;
#pragma unroll
            for (int j = 0; j < 2; ++j) {
                int row = sr + 64 * j;
                int off = ldsoff(row, sc);
                *(bf16x8*)&sBh[off] =
                    *(const bf16x8*)&Bh[(long long)(n0 + row) * ldb + k0 + sc];
                if constexpr (SPLIT) {
                    const __bf16* Bl = (const __bf16*)Blp + bz * sB;
                    *(bf16x8*)&sBl[off] =
                        *(const bf16x8*)&Bl[(long long)(n0 + row) * ldb + k0 + sc];
                }
            }
        }
        __syncthreads();

        // ---- fragments + MFMA ----
        bf16x8 fah[4], fbh[4];
        bf16x8 fal[4], fbl[4];
#pragma unroll
        for (int i = 0; i < 4; ++i) {
            fah[i] = *(const bf16x8*)&sAh[abase + i * 512];
            fbh[i] = *(const bf16x8*)&sBh[bbase + i * 512];
            if constexpr (SPLIT) {
                fal[i] = *(const bf16x8*)&sAl[abase + i * 512];
                fbl[i] = *(const bf16x8*)&sBl[bbase + i * 512];
            }
        }
#pragma unroll
        for (int i = 0; i < 4; ++i)
#pragma unroll
            for (int j = 0; j < 4; ++j) {
                if constexpr (SPLIT) {
                    acc[i][j] = __builtin_amdgcn_mfma_f32_16x16x32_bf16(fal[i], fbh[j], acc[i][j], 0, 0, 0);
                    acc[i][j] = __builtin_amdgcn_mfma_f32_16x16x32_bf16(fah[i], fbl[j], acc[i][j], 0, 0, 0);
                }
                acc[i][j] = __builtin_amdgcn_mfma_f32_16x16x32_bf16(fah[i], fbh[j], acc[i][j], 0, 0, 0);
            }
        __syncthreads();
    }

    // ---- epilogue: C[row][col], col = lane&15, row = quad*4 + r (m89-verified) ----
#pragma unroll
    for (int i = 0; i < 4; ++i)
#pragma unroll
        for (int j = 0; j < 4; ++j) {
            int col = n0 + wn + j * 16 + lr;
            int row0 = m0 + wm + i * 16 + quad * 4;
            float bv = bias ? bias[col] : 0.f;
#pragma unroll
            for (int r = 0; r < 4; ++r) {
                float v = acc[i][j][r] + bv;
                long long off = (long long)(row0 + r) * ldc + col + bz * sC;
                if constexpr (OUT_SPLIT) {
                    __bf16 h = (__bf16)v;
                    Chi[off] = h;
                    Clo[off] = (__bf16)(v - (float)h);
                } else {
                    Cf[off] = v;
                }
            }
        }
}

// ---------------- fp32 tiled GEMM (small/fold/residual gemms) -------------------
#define GTS 64
#define GKT 16
#define GPAD 68

template<int TRANSB, int RELU, int TRANSC>
__global__ __launch_bounds__(256) void gemm_f32(
    const float* __restrict__ A, int lda, long long sA,
    const float* __restrict__ Bm, int ldb, long long sB,
    const float* __restrict__ bias,
    float* __restrict__ C, int ldc, long long sC,
    int M, int N, int K)
{
    __shared__ float As[GKT][GPAD];
    __shared__ float Bs[GKT][GPAD];
    const int tid = threadIdx.x;
    const int tx = tid & 15, ty = tid >> 4;
    const int n0 = blockIdx.x * GTS;
    const int m0 = blockIdx.y * GTS;
    const long long bz = blockIdx.z;
    const float* Ab = A + bz * sA;
    const float* Bb = Bm + bz * sB;
    float* Cb = C + bz * sC;

    const int lr = tid >> 2;
    const int lc = (tid & 3) << 2;
    const int br = tid >> 4;
    const int bc = (tid & 15) << 2;

    float acc[4][4] = {};

    for (int k0 = 0; k0 < K; k0 += GKT) {
        float4 a = *(const float4*)&Ab[(long long)(m0 + lr) * lda + k0 + lc];
        As[lc + 0][lr] = a.x; As[lc + 1][lr] = a.y;
        As[lc + 2][lr] = a.z; As[lc + 3][lr] = a.w;
        if (TRANSB) {
            float4 b = *(const float4*)&Bb[(long long)(n0 + lr) * ldb + k0 + lc];
            Bs[lc + 0][lr] = b.x; Bs[lc + 1][lr] = b.y;
            Bs[lc + 2][lr] = b.z; Bs[lc + 3][lr] = b.w;
        } else {
            float4 b = *(const float4*)&Bb[(long long)(k0 + br) * ldb + n0 + bc];
            *(float4*)&Bs[br][bc] = b;
        }
        __syncthreads();
#pragma unroll
        for (int k = 0; k < GKT; ++k) {
            float4 av = *(const float4*)&As[k][ty << 2];
            float4 bv = *(const float4*)&Bs[k][tx << 2];
            float ar[4] = {av.x, av.y, av.z, av.w};
            float brr[4] = {bv.x, bv.y, bv.z, bv.w};
#pragma unroll
            for (int i = 0; i < 4; ++i)
#pragma unroll
                for (int j = 0; j < 4; ++j)
                    acc[i][j] = fmaf(ar[i], brr[j], acc[i][j]);
        }
        __syncthreads();
    }

    float bbr[4] = {0.f, 0.f, 0.f, 0.f};
    if (bias) {
        float4 bb = *(const float4*)&bias[n0 + (tx << 2)];
        bbr[0] = bb.x; bbr[1] = bb.y; bbr[2] = bb.z; bbr[3] = bb.w;
    }
#pragma unroll
    for (int i = 0; i < 4; ++i) {
#pragma unroll
        for (int j = 0; j < 4; ++j) {
            float o = acc[i][j] + bbr[j];
            if (RELU) o = fmaxf(o, 0.f);
            if (TRANSC)
                Cb[(long long)(n0 + (tx << 2) + j) * ldc + m0 + (ty << 2) + i] = o;
            else
                Cb[(long long)(m0 + (ty << 2) + i) * ldc + n0 + (tx << 2) + j] = o;
        }
    }
}

// ---------------- word_pe: scan + table + streaming add/split -------------------
// pe depends only on (count, c); count = cumsum(mask) is an integer in [0,256]
// -> precompute a 257x256 table (bit-identical powf/sinf/cosf), then stream.

__global__ __launch_bounds__(256) void cumsum_kernel(
    const int* __restrict__ tm, int* __restrict__ cums)
{
    int b = blockIdx.x, c = threadIdx.x;
    int lane = c & 63;
    int v = (tm[(long long)b * LFULL + 1 + c] != 0) ? 1 : 0;
#pragma unroll
    for (int off = 1; off < 64; off <<= 1) {
        int t = __shfl_up(v, off);
        if (lane >= off) v += t;
    }
    __shared__ int wsum[4];
    if (lane == 63) wsum[c >> 6] = v;
    __syncthreads();
    int w = c >> 6, add = 0;
    for (int i = 0; i < w; ++i) add += wsum[i];
    cums[b * LW + c] = v + add;
}

__global__ __launch_bounds__(256) void pe_table_kernel(float* __restrict__ petab)
{
    int n = blockIdx.x;          // count value 0..256
    int c = threadIdx.x;
    int i2 = c & ~1;
    float freq = powf(10000.0f, (float)i2 / (float)CC);
    float arg = (float)n / freq;
    petab[n * CC + c] = (c & 1) ? cosf(arg) : sinf(arg);
}

__global__ __launch_bounds__(256) void word_pe2_kernel(
    const float* __restrict__ te, const int* __restrict__ cums,
    const float* __restrict__ petab,
    __bf16* __restrict__ whi, __bf16* __restrict__ wlo)
{
    int g = blockIdx.x * 256 + threadIdx.x;   // 0 .. 128*256*64-1
    int c0 = (g & 63) << 2;                   // channel base (float4)
    int l  = (g >> 6) & 255;
    int b  = g >> 14;
    int cnt = cums[b * LW + l];
    float4 s = *(const float4*)&te[((long long)(b * LFULL + 1 + l)) * CC + c0];
    float4 p = *(const float4*)&petab[cnt * CC + c0];
    float v0 = s.x + p.x, v1 = s.y + p.y, v2 = s.z + p.z, v3 = s.w + p.w;
    bf16x4 h, lo;
    h[0] = (__bf16)v0; lo[0] = (__bf16)(v0 - (float)h[0]);
    h[1] = (__bf16)v1; lo[1] = (__bf16)(v1 - (float)h[1]);
    h[2] = (__bf16)v2; lo[2] = (__bf16)(v2 - (float)h[2]);
    h[3] = (__bf16)v3; lo[3] = (__bf16)(v3 - (float)h[3]);
    long long o = ((long long)(b * LW + l)) * CC + c0;
    *(bf16x4*)&whi[o] = h;
    *(bf16x4*)&wlo[o] = lo;
}

// ---------------- weight prep -------------------------------------------------
__global__ __launch_bounds__(256) void split_transpose_kernel(
    const float* __restrict__ W, __bf16* __restrict__ hi, __bf16* __restrict__ lo)
{
    int n = blockIdx.x, k = threadIdx.x;
    float v = W[(long long)k * CC + n];
    __bf16 h = (__bf16)v;
    hi[(long long)n * CC + k] = h;
    lo[(long long)n * CC + k] = (__bf16)(v - (float)h);
}
__global__ __launch_bounds__(256) void split_plain_kernel(
    const float* __restrict__ W, __bf16* __restrict__ hi, __bf16* __restrict__ lo)
{
    int g = blockIdx.x * 256 + threadIdx.x;
    float v = W[g];
    __bf16 h = (__bf16)v;
    hi[g] = h;
    lo[g] = (__bf16)(v - (float)h);
}
__global__ __launch_bounds__(256) void cvt_bf16_kernel(
    const float* __restrict__ src, __bf16* __restrict__ dst)
{
    int g = blockIdx.x * 256 + threadIdx.x;
    dst[g] = (__bf16)src[g];
}

// ---------------- in-place softmax over T + entropy ----------------------------
__global__ __launch_bounds__(256) void softmax_entropy_kernel(
    float* __restrict__ attn, const int* __restrict__ vmask,
    float* __restrict__ ent)
{
    __shared__ float lds[4];
    long long row = blockIdx.x;
    int b = blockIdx.x >> 8;
    float* p = attn + row * TT;
    const int* m = vmask + (long long)b * TT;
    int t4 = threadIdx.x * 4;
    float4 v = *(const float4*)&p[t4];
    int4 mm4 = *(const int4*)&m[t4];
    float x[4];
    x[0] = mm4.x ? v.x : -INFINITY;
    x[1] = mm4.y ? v.y : -INFINITY;
    x[2] = mm4.z ? v.z : -INFINITY;
    x[3] = mm4.w ? v.w : -INFINITY;
    float mx = fmaxf(fmaxf(x[0], x[1]), fmaxf(x[2], x[3]));
    mx = blockReduceMax(mx, lds);
    float e[4];
    float ps = 0.f;
#pragma unroll
    for (int j = 0; j < 4; ++j) { e[j] = expf(x[j] - mx); ps += e[j]; }
    float sum = blockReduceSum(ps, lds);
    float q[4];
    float ce = 0.f;
#pragma unroll
    for (int j = 0; j < 4; ++j) {
        q[j] = e[j] / sum;
        ce += q[j] * logf(q[j] + 1e-6f);
    }
    ce = blockReduceSum(ce, lds);
    *(float4*)&p[t4] = make_float4(q[0], q[1], q[2], q[3]);
    if (threadIdx.x == 0) ent[row] = -ce;
}

// ---------------- greedy selection ---------------------------------------------
__global__ __launch_bounds__(256) void select_kernel(
    const float* __restrict__ ent, const int* __restrict__ tm,
    int* __restrict__ sel)
{
    int b = blockIdx.x;
    int l = threadIdx.x;
    __shared__ float sc[LW];
    __shared__ int ord[LW];
    __shared__ unsigned char mk[LW];
    mk[l] = (tm[(long long)b * LFULL + 1 + l] != 0);
    sc[l] = mk[l] ? ent[(long long)b * LW + l] : -INFINITY;
    __syncthreads();
    float mys = sc[l];
    int r = 0;
    for (int j = 0; j < LW; ++j) {
        float s = sc[j];
        r += (s > mys) || (s == mys && j < l);
    }
    ord[r] = l;
    __syncthreads();
    if (l == 0) {
        int chosen[PP];
        int cnt = 0;
        for (int t = 0; t < LW; ++t) {
            int idx = ord[t];
            if (!mk[idx]) continue;
            if (cnt >= PP) break;
            bool ok = true;
            for (int s2 = 0; s2 < cnt; ++s2) {
                int d = idx - chosen[s2];
                if (d < 0) d = -d;
                if (d < 2) ok = false;
            }
            if (ok) chosen[cnt++] = idx;
        }
        int last = (cnt > 0) ? chosen[cnt - 1] : -1;
        for (int p = 0; p < PP; ++p)
            sel[b * PP + p] = (p < cnt) ? chosen[p] : last;
    }
}

// ---------------- gather selected rows of word_pe (hi+lo) ----------------------
__global__ __launch_bounds__(256) void gather_kernel(
    const __bf16* __restrict__ whi, const __bf16* __restrict__ wlo,
    const int* __restrict__ sel, float* __restrict__ x0)
{
    int g = blockIdx.x * 256 + threadIdx.x;
    int b = g >> 11;
    int p = (g >> 8) & 7;
    int c = g & 255;
    int idx = sel[b * PP + p];
    if (idx < 0) idx = 0;
    long long off = ((long long)b * LW + idx) * CC + c;
    x0[g] = (float)whi[off] + (float)wlo[off];
}

// ---------------- effective biases ---------------------------------------------
__global__ __launch_bounds__(256) void eff_bias_kernel(
    const float* __restrict__ q_b, const float* __restrict__ kv_b,
    const float* __restrict__ in_w, const float* __restrict__ in_b,
    float* __restrict__ BQE_all, float* __restrict__ bkv3)
{
    int i = blockIdx.x / 3;
    int role = blockIdx.x % 3;
    int n = threadIdx.x;
    const float* inw = in_w + (long long)i * 196608;
    const float* inb = in_b + (long long)i * 768;
    const float* srcb;
    int co;
    float* dst;
    if (role == 0)      { srcb = q_b + i * 256;        co = 0;   dst = BQE_all + i * 256; }
    else if (role == 1) { srcb = kv_b + i * 512;       co = 256; dst = bkv3 + i * 512; }
    else                { srcb = kv_b + i * 512 + 256; co = 512; dst = bkv3 + i * 512 + 256; }
    float s = inb[co + n];
    for (int k = 0; k < CC; ++k)
        s = fmaf(srcb[k], inw[(long long)k * 768 + co + n], s);
    dst[n] = s;
}

// ---------------- attention scores + softmax (block per (b,h)); KV ld=512 ------
__global__ __launch_bounds__(256) void attn_scores_kernel(
    const float* __restrict__ qp, const float* __restrict__ KV,
    const int* __restrict__ tm, float* __restrict__ attn)
{
    int b = blockIdx.x, h = blockIdx.y;
    int tid = threadIdx.x;
    __shared__ float qs[PP][DHD];
    __shared__ float sc[PP][LW];
    __shared__ float mxs[PP], sms[PP];
    {
        int q = tid >> 5, d = tid & 31;
        qs[q][d] = qp[((long long)(b * PP + q)) * CC + h * DHD + d];
    }
    __syncthreads();
    const float* kr = KV + ((long long)(b * LW + tid)) * 512 + h * DHD;
    float kreg[DHD];
#pragma unroll
    for (int j = 0; j < 8; ++j) {
        float4 f = *(const float4*)&kr[j * 4];
        kreg[j * 4 + 0] = f.x; kreg[j * 4 + 1] = f.y;
        kreg[j * 4 + 2] = f.z; kreg[j * 4 + 3] = f.w;
    }
    bool mk = tm[(long long)b * LFULL + 1 + tid] != 0;
#pragma unroll
    for (int q = 0; q < PP; ++q) {
        float s = 0.f;
#pragma unroll
        for (int d = 0; d < DHD; ++d) s = fmaf(qs[q][d], kreg[d], s);
        sc[q][tid] = mk ? s * 0.17677669529663687f : -INFINITY;
    }
    __syncthreads();
    {
        int q = tid >> 5, j = tid & 31;
        float m = -INFINITY;
        for (int kk = j; kk < LW; kk += 32) m = fmaxf(m, sc[q][kk]);
#pragma unroll
        for (int mm = 16; mm >= 1; mm >>= 1) m = fmaxf(m, __shfl_xor(m, mm, 32));
        float s = 0.f;
        for (int kk = j; kk < LW; kk += 32) s += expf(sc[q][kk] - m);
#pragma unroll
        for (int mm = 16; mm >= 1; mm >>= 1) s += __shfl_xor(s, mm, 32);
        if (j == 0) { mxs[q] = m; sms[q] = s; }
    }
    __syncthreads();
#pragma unroll
    for (int q = 0; q < PP; ++q) {
        float pv = expf(sc[q][tid] - mxs[q]) / sms[q];
        attn[(((long long)(b * NH + h)) * PP + q) * LW + tid] = pv;
    }
}

// ---------------- attn @ V (block per (b,q)); V at KV col offset 256 -----------
__global__ __launch_bounds__(256) void attn_out_kernel(
    const float* __restrict__ attn, const float* __restrict__ KV,
    float* __restrict__ aout)
{
    int b = blockIdx.x, q = blockIdx.y;
    int c = threadIdx.x, h = c >> 5;
    __shared__ float att[NH][LW];
#pragma unroll
    for (int hh = 0; hh < NH; ++hh)
        att[hh][c] = attn[(((long long)(b * NH + hh)) * PP + q) * LW + c];
    __syncthreads();
    const float* vpb = KV + ((long long)b * LW) * 512 + 256 + c;
    float acc = 0.f;
#pragma unroll 8
    for (int k = 0; k < LW; ++k)
        acc = fmaf(att[h][k], vpb[(long long)k * 512], acc);
    aout[((long long)(b * PP + q)) * CC + c] = acc;
}

// ---------------- slot_sim = mean over heads -----------------------------------
__global__ __launch_bounds__(256) void slot_sim_kernel(
    const float* __restrict__ attn, float* __restrict__ outs)
{
    int b = blockIdx.x, q = blockIdx.y, k = threadIdx.x;
    float s = 0.f;
#pragma unroll
    for (int h = 0; h < NH; ++h)
        s += attn[(((long long)(b * NH + h)) * PP + q) * LW + k];
    outs[((long long)(b * PP + q)) * LW + k] = s * 0.125f;
}

// ---------------- residual + layer norm ----------------------------------------
__global__ __launch_bounds__(256) void ln_residual_kernel(
    const float* __restrict__ xin, const float* __restrict__ add,
    const float* __restrict__ g, const float* __restrict__ bta,
    float* __restrict__ out)
{
    __shared__ float lds[4];
    int r = blockIdx.x, c = threadIdx.x;
    long long idx = (long long)r * CC + c;
    float v = xin[idx] + add[idx];
    float s = blockReduceSum(v, lds);
    float mu = s * (1.0f / (float)CC);
    float d = v - mu;
    float var = blockReduceSum(d * d, lds) * (1.0f / (float)CC);
    out[idx] = d / sqrtf(var + 1e-5f) * g[c] + bta[c];
}

// ---------------- eos broadcast -------------------------------------------------
__global__ __launch_bounds__(256) void eos_kernel(
    const float* __restrict__ eos, float* __restrict__ outp)
{
    outp[(long long)blockIdx.x * CC + threadIdx.x] = eos[threadIdx.x];
}

// =================================================================================
extern "C" void kernel_launch(void* const* d_in, const int* in_sizes, int n_in,
                              void* d_out, int out_size, void* d_ws, size_t ws_size,
                              hipStream_t stream) {
    const float* txt_emb     = (const float*)d_in[0];
    const int*   txt_mask    = (const int*)d_in[1];
    const float* video_feats = (const float*)d_in[2];
    const int*   video_mask  = (const int*)d_in[3];
    const float* word_proj_w = (const float*)d_in[4];
    const float* word_proj_b = (const float*)d_in[5];
    const float* video_proj_w = (const float*)d_in[6];
    // video_proj_b drops out (softmax shift invariance)
    const float* q_w   = (const float*)d_in[8];
    const float* q_b   = (const float*)d_in[9];
    const float* kv_w  = (const float*)d_in[10];
    const float* kv_b  = (const float*)d_in[11];
    const float* in_w  = (const float*)d_in[12];
    const float* in_b  = (const float*)d_in[13];
    const float* out_w = (const float*)d_in[14];
    const float* out_b = (const float*)d_in[15];
    const float* ln0_g = (const float*)d_in[16];
    const float* ln0_b = (const float*)d_in[17];
    const float* lin_w = (const float*)d_in[18];
    const float* lin_b = (const float*)d_in[19];
    const float* ln1_g = (const float*)d_in[20];
    const float* ln1_b = (const float*)d_in[21];
    const float* eos_slot = (const float*)d_in[22];

    // workspace layout (float units, ~120 MiB)
    float* ws = (float*)d_ws;
    __bf16* wpe_hi = (__bf16*)(ws + 0LL);          // 8388608 bf16
    __bf16* wpe_lo = (__bf16*)(ws + 4194304LL);    // 8388608 bf16
    __bf16* wp_hi  = (__bf16*)(ws + 8388608LL);
    __bf16* wp_lo  = (__bf16*)(ws + 12582912LL);
    __bf16* U_hi   = (__bf16*)(ws + 16777216LL);
    __bf16* U_lo   = (__bf16*)(ws + 20971520LL);
    float*  KV     = ws + 8388608LL;               // 32768x512 fp32 (overlaps wp/U)
    float* ent     = ws + 25165824LL;              // 32768
    int*   sel     = (int*)(ws + 25198592LL);      // 1024
    float* x0      = ws + 25199616LL;
    float* x1      = ws + 25461760LL;
    float* xmid    = ws + 25723904LL;
    float* qp      = ws + 25986048LL;
    float* attnw   = ws + 26248192LL;              // 2097152
    float* aout    = ws + 28345344LL;
    float* qatt    = ws + 28607488LL;
    float* upd     = ws + 28869632LL;
    float* WQE_all = ws + 29131776LL;              // 3*65536
    float* BQE_all = ws + 29328384LL;              // 768
    float* WT3f    = ws + 29329152LL;              // 393216 (3 layers x [512][256])
    __bf16* WT3    = (__bf16*)(ws + 29722368LL);   // 393216 bf16
    float* bkv3    = ws + 29918976LL;              // 1536
    __bf16* WPT_hi = (__bf16*)(ws + 29920512LL);   // 65536 bf16
    __bf16* WPT_lo = (__bf16*)(ws + 29953280LL);
    __bf16* VPS_hi = (__bf16*)(ws + 29986048LL);
    __bf16* VPS_lo = (__bf16*)(ws + 30018816LL);

    // transient (dead before step 3 writes the wp_hi/KV region): cums + pe table
    int*   cums  = (int*)(ws + 8388608LL);         // 32768 ints
    float* petab = ws + 8421376LL;                 // 257*256 floats

    float* outp     = (float*)d_out;
    float* out_ps   = outp;
    float* out_attn = outp + 262144LL;
    float* out_slot = outp + 33816576LL;
    float* out_eos  = outp + 34078720LL;

    // 1. word_pe (split bf16): scan + table + streaming add/split
    cumsum_kernel<<<dim3(BB), dim3(256), 0, stream>>>(txt_mask, cums);
    pe_table_kernel<<<dim3(257), dim3(256), 0, stream>>>(petab);
    word_pe2_kernel<<<dim3(8192), dim3(256), 0, stream>>>(txt_emb, cums, petab, wpe_hi, wpe_lo);
    // 2. weight preps
    split_transpose_kernel<<<dim3(256), dim3(256), 0, stream>>>(word_proj_w, WPT_hi, WPT_lo);
    split_plain_kernel<<<dim3(256), dim3(256), 0, stream>>>(video_proj_w, VPS_hi, VPS_lo);
    // 3. wp = word_pe @ Wword + b   (split x split -> split out)
    gemm_mfma<1,0,1><<<dim3(2,256,1), dim3(256), 0, stream>>>(
        wpe_hi, wpe_lo, 256, 0, WPT_hi, WPT_lo, 256, 0, word_proj_b,
        nullptr, wp_hi, wp_lo, 256, 0, 32768, 256, 256);
    // 4. U = wp @ Wvid^T            (split x split -> split out)
    gemm_mfma<1,0,1><<<dim3(2,256,1), dim3(256), 0, stream>>>(
        wp_hi, wp_lo, 256, 0, VPS_hi, VPS_lo, 256, 0, nullptr,
        nullptr, U_hi, U_lo, 256, 0, 32768, 256, 256);
    // 5. sim = U[b] @ video[b]^T    (split x fp32-in-kernel -> fp32 out_attn)
    gemm_mfma<1,1,0><<<dim3(8,2,BB), dim3(256), 0, stream>>>(
        U_hi, U_lo, 256, 65536LL, video_feats, nullptr, 256, 262144LL, nullptr,
        out_attn, nullptr, nullptr, 1024, 262144LL, 256, 1024, 256);
    // 6. softmax + entropy (in place)
    softmax_entropy_kernel<<<dim3(32768), dim3(256), 0, stream>>>(out_attn, video_mask, ent);
    // 7. selection + gather
    select_kernel<<<dim3(BB), dim3(256), 0, stream>>>(ent, txt_mask, sel);
    gather_kernel<<<dim3(1024), dim3(256), 0, stream>>>(wpe_hi, wpe_lo, sel, x0);

    // 8. folded weights (all layers, z-batched)
    gemm_f32<0,0,0><<<dim3(4,4,3), dim3(256), 0, stream>>>(
        q_w,256,65536LL, in_w,768,196608LL, nullptr, WQE_all,256,65536LL, 256,256,256);
    gemm_f32<0,0,1><<<dim3(4,4,3), dim3(256), 0, stream>>>(
        kv_w,512,131072LL, in_w+256,768,196608LL, nullptr, WT3f,256,131072LL, 256,256,256);
    gemm_f32<0,0,1><<<dim3(4,4,3), dim3(256), 0, stream>>>(
        kv_w+256,512,131072LL, in_w+512,768,196608LL, nullptr, WT3f+65536,256,131072LL, 256,256,256);
    eff_bias_kernel<<<dim3(9), dim3(256), 0, stream>>>(q_b, kv_b, in_w, in_b, BQE_all, bkv3);
    cvt_bf16_kernel<<<dim3(1536), dim3(256), 0, stream>>>(WT3f, (__bf16*)WT3);

    float* X = x0;
    for (int i = 0; i < NLAY; ++i) {
        const float* ow  = out_w + (long long)i * 65536;
        const float* ob  = out_b + (long long)i * 256;
        const float* g0  = ln0_g + (long long)i * 256;
        const float* b0  = ln0_b + (long long)i * 256;
        const float* lw  = lin_w + (long long)i * 65536;
        const float* lb  = lin_b + (long long)i * 256;
        const float* g1  = ln1_g + (long long)i * 256;
        const float* b1  = ln1_b + (long long)i * 256;

        gemm_mfma<0,0,0><<<dim3(4,256,1), dim3(256), 0, stream>>>(
            wpe_hi, nullptr, 256, 0, WT3 + (long long)i * 131072, nullptr, 256, 0,
            bkv3 + i * 512, KV, nullptr, nullptr, 512, 0, 32768, 512, 256);

        gemm_f32<0,0,0><<<dim3(4,16,1), dim3(256), 0, stream>>>(
            X,256,0, WQE_all + (long long)i*65536,256,0, BQE_all + i*256, qp,256,0, 1024,256,256);

        attn_scores_kernel<<<dim3(BB,NH), dim3(256), 0, stream>>>(qp, KV, txt_mask, attnw);
        attn_out_kernel<<<dim3(BB,PP), dim3(256), 0, stream>>>(attnw, KV, aout);
        if (i == NLAY - 1)
            slot_sim_kernel<<<dim3(BB,PP), dim3(256), 0, stream>>>(attnw, out_slot);

        gemm_f32<0,0,0><<<dim3(4,16,1), dim3(256), 0, stream>>>(
            aout,256,0, ow,256,0, ob, qatt,256,0, 1024,256,256);
        ln_residual_kernel<<<dim3(1024), dim3(256), 0, stream>>>(X, qatt, g0, b0, xmid);
        gemm_f32<0,1,0><<<dim3(4,16,1), dim3(256), 0, stream>>>(
            xmid,256,0, lw,256,0, lb, upd,256,0, 1024,256,256);
        float* Xout = (i == NLAY - 1) ? out_ps : ((X == x0) ? x1 : x0);
        ln_residual_kernel<<<dim3(1024), dim3(256), 0, stream>>>(xmid, upd, g1, b1, Xout);
        X = Xout;
    }
    eos_kernel<<<dim3(BB), dim3(256), 0, stream>>>(eos_slot, out_eos);
}

// Round 3
// 894.138 us; speedup vs baseline: 1.0233x; 1.0233x over previous
//
#include <hip/hip_runtime.h>
#include <math.h>

// Problem constants (fixed by setup_inputs)
#define BB 128
#define LFULL 257
#define LW 256     // L-1 words
#define TT 1024    // video frames
#define CC 256     // hidden
#define NH 8
#define DHD 32
#define PP 8       // NUM_PHRASE
#define NLAY 3

typedef __bf16 bf16x8 __attribute__((ext_vector_type(8)));
typedef __bf16 bf16x4 __attribute__((ext_vector_type(4)));
typedef float  f32x4  __attribute__((ext_vector_type(4)));

// ---------------- block reduce helpers (blockDim == 256 -> 4 waves) -------------
__device__ __forceinline__ float blockReduceSum(float v, volatile float* lds) {
#pragma unroll
    for (int m = 32; m >= 1; m >>= 1) v += __shfl_xor(v, m);
    __syncthreads();
    if ((threadIdx.x & 63) == 0) lds[threadIdx.x >> 6] = v;
    __syncthreads();
    return lds[0] + lds[1] + lds[2] + lds[3];
}
__device__ __forceinline__ float blockReduceMax(float v, volatile float* lds) {
#pragma unroll
    for (int m = 32; m >= 1; m >>= 1) v = fmaxf(v, __shfl_xor(v, m));
    __syncthreads();
    if ((threadIdx.x & 63) == 0) lds[threadIdx.x >> 6] = v;
    __syncthreads();
    return fmaxf(fmaxf(lds[0], lds[1]), fmaxf(lds[2], lds[3]));
}

// =================================================================================
// MFMA GEMM: C = A @ B^T (+bias).  A: M x K row-major bf16 (hi[,lo]).
// B: N x K row-major, either bf16 hi[,lo] (B_F32=0) or fp32 split in-kernel (B_F32=1).
// SPLIT=1: split-bf16 product (3 MFMAs) ~ fp32 accuracy. OUT_SPLIT=1: bf16 hi/lo out.
//
// ROUND-3 STRUCTURE: 128x128 block tile, BK=32, **512 threads = 8 waves**, each
// wave owns a 64x32 sub-tile (wm=(wv&1)*64, wn=(wv>>1)*32) with 4x2 16x16x32 frags.
// Rationale (r2 post-mortem): the old 4-wave/64x64 layout needed 64 AGPR acc +
// ~100 VGPR = ~164 regs -> 2 waves/SIMD (m69 step at 128) -> ~2 blocks/CU ->
// 20% occupancy -> the load/barrier/MFMA chain ran with near-zero overlap
// (MfmaUtil 18%, VALU 22%, HBM 36%, none saturated). 64x32 tiles halve acc to
// 32 AGPR; __launch_bounds__(512,4) caps combined regs at 128 -> 4 waves/SIMD.
// LDS conflicts were NOT the binding constraint (8.4M vs 12.6M at equal time),
// but the 512-thread staging also makes every LDS write 16B-contiguous per wave
// (conflict-free) as a side effect.
// LDS: fragment-ordered layout, reads linear-in-lane (conflict-free), 32 KB.
// =================================================================================

__device__ __forceinline__ int ldsoff(int row, int col) {
    // row 0..127, col 0..31, returns bf16-element offset into a 4096-elem buffer
    return ((row >> 6) << 11)
         + ((((row >> 4) & 3) << 2) + (col >> 3)) * 128
         + ((row & 15) << 3) + (col & 7);
}

template<int SPLIT, int B_F32, int OUT_SPLIT>
__global__ __launch_bounds__(512, 4) void gemm_mfma(
    const __bf16* __restrict__ Ahi, const __bf16* __restrict__ Alo, int lda, long long sA,
    const void* __restrict__ Bhp, const void* __restrict__ Blp, int ldb, long long sB,
    const float* __restrict__ bias,
    float* __restrict__ Cf, __bf16* __restrict__ Chi, __bf16* __restrict__ Clo,
    int ldc, long long sC, int M, int N, int K)
{
    __shared__ __bf16 sAh[4096];
    __shared__ __bf16 sAl[SPLIT ? 4096 : 1];
    __shared__ __bf16 sBh[4096];
    __shared__ __bf16 sBl[SPLIT ? 4096 : 1];

    const int tid = threadIdx.x;
    const int n0 = blockIdx.x * 128;
    const int m0 = blockIdx.y * 128;
    const long long bz = blockIdx.z;
    const __bf16* Ah = Ahi + bz * sA;
    const __bf16* Al = SPLIT ? (Alo + bz * sA) : nullptr;

    const int wv = tid >> 6, lane = tid & 63;
    const int wm = (wv & 1) << 6;          // 0 / 64
    const int wn = (wv >> 1) << 5;         // 0 / 32 / 64 / 96
    const int lr = lane & 15, quad = lane >> 4;

    // staging indices: 512 threads cover 128 rows x 32 cols, 8 elems each
    const int sr = tid >> 2;               // 0..127
    const int sc = (tid & 3) << 3;         // 0,8,16,24

    // fragment-read bases (bf16 elems): linear in lane -> conflict-free b128 reads
    const int abase = ((wm >> 6) << 11) + (lane << 3);
    const int bbase = ((wn >> 6) << 11) + (((wn >> 4) & 3) << 9) + (lane << 3);

    f32x4 acc[4][2];
#pragma unroll
    for (int i = 0; i < 4; ++i)
#pragma unroll
        for (int j = 0; j < 2; ++j) acc[i][j] = (f32x4)(0.f);

    for (int k0 = 0; k0 < K; k0 += 32) {
        // ---- stage A (bf16 hi[,lo]) ----
        {
            int off = ldsoff(sr, sc);
            *(bf16x8*)&sAh[off] =
                *(const bf16x8*)&Ah[(long long)(m0 + sr) * lda + k0 + sc];
            if constexpr (SPLIT)
                *(bf16x8*)&sAl[off] =
                    *(const bf16x8*)&Al[(long long)(m0 + sr) * lda + k0 + sc];
        }
        // ---- stage B ----
        if constexpr (B_F32) {
            const float* Bf = (const float*)Bhp + bz * sB;
            const float* src = &Bf[(long long)(n0 + sr) * ldb + k0 + sc];
            float4 f0 = *(const float4*)&src[0];
            float4 f1 = *(const float4*)&src[4];
            bf16x8 h8, l8;
            h8[0] = (__bf16)f0.x; l8[0] = (__bf16)(f0.x - (float)h8[0]);
            h8[1] = (__bf16)f0.y; l8[1] = (__bf16)(f0.y - (float)h8[1]);
            h8[2] = (__bf16)f0.z; l8[2] = (__bf16)(f0.z - (float)h8[2]);
            h8[3] = (__bf16)f0.w; l8[3] = (__bf16)(f0.w - (float)h8[3]);
            h8[4] = (__bf16)f1.x; l8[4] = (__bf16)(f1.x - (float)h8[4]);
            h8[5] = (__bf16)f1.y; l8[5] = (__bf16)(f1.y - (float)h8[5]);
            h8[6] = (__bf16)f1.z; l8[6] = (__bf16)(f1.z - (float)h8[6]);
            h8[7] = (__bf16)f1.w; l8[7] = (__bf16)(f1.w - (float)h8[7]);
            int off = ldsoff(sr, sc);
            *(bf16x8*)&sBh[off] = h8;
            *(bf16x8*)&sBl[off] = l8;
        } else {
            const __bf16* Bh = (const __bf16*)Bhp + bz * sB;
            int off = ldsoff(sr, sc);
            *(bf16x8*)&sBh[off] =
                *(const bf16x8*)&Bh[(long long)(n0 + sr) * ldb + k0 + sc];
            if constexpr (SPLIT) {
                const __bf16* Bl = (const __bf16*)Blp + bz * sB;
                *(bf16x8*)&sBl[off] =
                    *(const bf16x8*)&Bl[(long long)(n0 + sr) * ldb + k0 + sc];
            }
        }
        __syncthreads();

        // ---- fragments + MFMA ----
        bf16x8 fah[4], fbh[2];
        bf16x8 fal[4], fbl[2];
#pragma unroll
        for (int i = 0; i < 4; ++i) {
            fah[i] = *(const bf16x8*)&sAh[abase + i * 512];
            if constexpr (SPLIT)
                fal[i] = *(const bf16x8*)&sAl[abase + i * 512];
        }
#pragma unroll
        for (int j = 0; j < 2; ++j) {
            fbh[j] = *(const bf16x8*)&sBh[bbase + j * 512];
            if constexpr (SPLIT)
                fbl[j] = *(const bf16x8*)&sBl[bbase + j * 512];
        }
#pragma unroll
        for (int i = 0; i < 4; ++i)
#pragma unroll
            for (int j = 0; j < 2; ++j) {
                if constexpr (SPLIT) {
                    acc[i][j] = __builtin_amdgcn_mfma_f32_16x16x32_bf16(fal[i], fbh[j], acc[i][j], 0, 0, 0);
                    acc[i][j] = __builtin_amdgcn_mfma_f32_16x16x32_bf16(fah[i], fbl[j], acc[i][j], 0, 0, 0);
                }
                acc[i][j] = __builtin_amdgcn_mfma_f32_16x16x32_bf16(fah[i], fbh[j], acc[i][j], 0, 0, 0);
            }
        __syncthreads();
    }

    // ---- epilogue: C[row][col], col = lane&15, row = quad*4 + r (m89-verified) ----
#pragma unroll
    for (int i = 0; i < 4; ++i)
#pragma unroll
        for (int j = 0; j < 2; ++j) {
            int col = n0 + wn + j * 16 + lr;
            int row0 = m0 + wm + i * 16 + quad * 4;
            float bv = bias ? bias[col] : 0.f;
#pragma unroll
            for (int r = 0; r < 4; ++r) {
                float v = acc[i][j][r] + bv;
                long long off = (long long)(row0 + r) * ldc + col + bz * sC;
                if constexpr (OUT_SPLIT) {
                    __bf16 h = (__bf16)v;
                    Chi[off] = h;
                    Clo[off] = (__bf16)(v - (float)h);
                } else {
                    Cf[off] = v;
                }
            }
        }
}

// ---------------- fp32 tiled GEMM (small/fold/residual gemms) -------------------
#define GTS 64
#define GKT 16
#define GPAD 68

template<int TRANSB, int RELU, int TRANSC>
__global__ __launch_bounds__(256) void gemm_f32(
    const float* __restrict__ A, int lda, long long sA,
    const float* __restrict__ Bm, int ldb, long long sB,
    const float* __restrict__ bias,
    float* __restrict__ C, int ldc, long long sC,
    int M, int N, int K)
{
    __shared__ float As[GKT][GPAD];
    __shared__ float Bs[GKT][GPAD];
    const int tid = threadIdx.x;
    const int tx = tid & 15, ty = tid >> 4;
    const int n0 = blockIdx.x * GTS;
    const int m0 = blockIdx.y * GTS;
    const long long bz = blockIdx.z;
    const float* Ab = A + bz * sA;
    const float* Bb = Bm + bz * sB;
    float* Cb = C + bz * sC;

    const int lr = tid >> 2;
    const int lc = (tid & 3) << 2;
    const int br = tid >> 4;
    const int bc = (tid & 15) << 2;

    float acc[4][4] = {};

    for (int k0 = 0; k0 < K; k0 += GKT) {
        float4 a = *(const float4*)&Ab[(long long)(m0 + lr) * lda + k0 + lc];
        As[lc + 0][lr] = a.x; As[lc + 1][lr] = a.y;
        As[lc + 2][lr] = a.z; As[lc + 3][lr] = a.w;
        if (TRANSB) {
            float4 b = *(const float4*)&Bb[(long long)(n0 + lr) * ldb + k0 + lc];
            Bs[lc + 0][lr] = b.x; Bs[lc + 1][lr] = b.y;
            Bs[lc + 2][lr] = b.z; Bs[lc + 3][lr] = b.w;
        } else {
            float4 b = *(const float4*)&Bb[(long long)(k0 + br) * ldb + n0 + bc];
            *(float4*)&Bs[br][bc] = b;
        }
        __syncthreads();
#pragma unroll
        for (int k = 0; k < GKT; ++k) {
            float4 av = *(const float4*)&As[k][ty << 2];
            float4 bv = *(const float4*)&Bs[k][tx << 2];
            float ar[4] = {av.x, av.y, av.z, av.w};
            float brr[4] = {bv.x, bv.y, bv.z, bv.w};
#pragma unroll
            for (int i = 0; i < 4; ++i)
#pragma unroll
                for (int j = 0; j < 4; ++j)
                    acc[i][j] = fmaf(ar[i], brr[j], acc[i][j]);
        }
        __syncthreads();
    }

    float bbr[4] = {0.f, 0.f, 0.f, 0.f};
    if (bias) {
        float4 bb = *(const float4*)&bias[n0 + (tx << 2)];
        bbr[0] = bb.x; bbr[1] = bb.y; bbr[2] = bb.z; bbr[3] = bb.w;
    }
#pragma unroll
    for (int i = 0; i < 4; ++i) {
#pragma unroll
        for (int j = 0; j < 4; ++j) {
            float o = acc[i][j] + bbr[j];
            if (RELU) o = fmaxf(o, 0.f);
            if (TRANSC)
                Cb[(long long)(n0 + (tx << 2) + j) * ldc + m0 + (ty << 2) + i] = o;
            else
                Cb[(long long)(m0 + (ty << 2) + i) * ldc + n0 + (tx << 2) + j] = o;
        }
    }
}

// ---------------- word_pe: scan + table + streaming add/split -------------------
// pe depends only on (count, c); count = cumsum(mask) is an integer in [0,256]
// -> precompute a 257x256 table (bit-identical powf/sinf/cosf), then stream.

__global__ __launch_bounds__(256) void cumsum_kernel(
    const int* __restrict__ tm, int* __restrict__ cums)
{
    int b = blockIdx.x, c = threadIdx.x;
    int lane = c & 63;
    int v = (tm[(long long)b * LFULL + 1 + c] != 0) ? 1 : 0;
#pragma unroll
    for (int off = 1; off < 64; off <<= 1) {
        int t = __shfl_up(v, off);
        if (lane >= off) v += t;
    }
    __shared__ int wsum[4];
    if (lane == 63) wsum[c >> 6] = v;
    __syncthreads();
    int w = c >> 6, add = 0;
    for (int i = 0; i < w; ++i) add += wsum[i];
    cums[b * LW + c] = v + add;
}

__global__ __launch_bounds__(256) void pe_table_kernel(float* __restrict__ petab)
{
    int n = blockIdx.x;          // count value 0..256
    int c = threadIdx.x;
    int i2 = c & ~1;
    float freq = powf(10000.0f, (float)i2 / (float)CC);
    float arg = (float)n / freq;
    petab[n * CC + c] = (c & 1) ? cosf(arg) : sinf(arg);
}

__global__ __launch_bounds__(256) void word_pe2_kernel(
    const float* __restrict__ te, const int* __restrict__ cums,
    const float* __restrict__ petab,
    __bf16* __restrict__ whi, __bf16* __restrict__ wlo)
{
    int g = blockIdx.x * 256 + threadIdx.x;   // 0 .. 128*256*64-1
    int c0 = (g & 63) << 2;                   // channel base (float4)
    int l  = (g >> 6) & 255;
    int b  = g >> 14;
    int cnt = cums[b * LW + l];
    float4 s = *(const float4*)&te[((long long)(b * LFULL + 1 + l)) * CC + c0];
    float4 p = *(const float4*)&petab[cnt * CC + c0];
    float v0 = s.x + p.x, v1 = s.y + p.y, v2 = s.z + p.z, v3 = s.w + p.w;
    bf16x4 h, lo;
    h[0] = (__bf16)v0; lo[0] = (__bf16)(v0 - (float)h[0]);
    h[1] = (__bf16)v1; lo[1] = (__bf16)(v1 - (float)h[1]);
    h[2] = (__bf16)v2; lo[2] = (__bf16)(v2 - (float)h[2]);
    h[3] = (__bf16)v3; lo[3] = (__bf16)(v3 - (float)h[3]);
    long long o = ((long long)(b * LW + l)) * CC + c0;
    *(bf16x4*)&whi[o] = h;
    *(bf16x4*)&wlo[o] = lo;
}

// ---------------- weight prep -------------------------------------------------
__global__ __launch_bounds__(256) void split_transpose_kernel(
    const float* __restrict__ W, __bf16* __restrict__ hi, __bf16* __restrict__ lo)
{
    int n = blockIdx.x, k = threadIdx.x;
    float v = W[(long long)k * CC + n];
    __bf16 h = (__bf16)v;
    hi[(long long)n * CC + k] = h;
    lo[(long long)n * CC + k] = (__bf16)(v - (float)h);
}
__global__ __launch_bounds__(256) void split_plain_kernel(
    const float* __restrict__ W, __bf16* __restrict__ hi, __bf16* __restrict__ lo)
{
    int g = blockIdx.x * 256 + threadIdx.x;
    float v = W[g];
    __bf16 h = (__bf16)v;
    hi[g] = h;
    lo[g] = (__bf16)(v - (float)h);
}
__global__ __launch_bounds__(256) void cvt_bf16_kernel(
    const float* __restrict__ src, __bf16* __restrict__ dst)
{
    int g = blockIdx.x * 256 + threadIdx.x;
    dst[g] = (__bf16)src[g];
}

// ---------------- in-place softmax over T + entropy ----------------------------
__global__ __launch_bounds__(256) void softmax_entropy_kernel(
    float* __restrict__ attn, const int* __restrict__ vmask,
    float* __restrict__ ent)
{
    __shared__ float lds[4];
    long long row = blockIdx.x;
    int b = blockIdx.x >> 8;
    float* p = attn + row * TT;
    const int* m = vmask + (long long)b * TT;
    int t4 = threadIdx.x * 4;
    float4 v = *(const float4*)&p[t4];
    int4 mm4 = *(const int4*)&m[t4];
    float x[4];
    x[0] = mm4.x ? v.x : -INFINITY;
    x[1] = mm4.y ? v.y : -INFINITY;
    x[2] = mm4.z ? v.z : -INFINITY;
    x[3] = mm4.w ? v.w : -INFINITY;
    float mx = fmaxf(fmaxf(x[0], x[1]), fmaxf(x[2], x[3]));
    mx = blockReduceMax(mx, lds);
    float e[4];
    float ps = 0.f;
#pragma unroll
    for (int j = 0; j < 4; ++j) { e[j] = expf(x[j] - mx); ps += e[j]; }
    float sum = blockReduceSum(ps, lds);
    float q[4];
    float ce = 0.f;
#pragma unroll
    for (int j = 0; j < 4; ++j) {
        q[j] = e[j] / sum;
        ce += q[j] * logf(q[j] + 1e-6f);
    }
    ce = blockReduceSum(ce, lds);
    *(float4*)&p[t4] = make_float4(q[0], q[1], q[2], q[3]);
    if (threadIdx.x == 0) ent[row] = -ce;
}

// ---------------- greedy selection ---------------------------------------------
__global__ __launch_bounds__(256) void select_kernel(
    const float* __restrict__ ent, const int* __restrict__ tm,
    int* __restrict__ sel)
{
    int b = blockIdx.x;
    int l = threadIdx.x;
    __shared__ float sc[LW];
    __shared__ int ord[LW];
    __shared__ unsigned char mk[LW];
    mk[l] = (tm[(long long)b * LFULL + 1 + l] != 0);
    sc[l] = mk[l] ? ent[(long long)b * LW + l] : -INFINITY;
    __syncthreads();
    float mys = sc[l];
    int r = 0;
    for (int j = 0; j < LW; ++j) {
        float s = sc[j];
        r += (s > mys) || (s == mys && j < l);
    }
    ord[r] = l;
    __syncthreads();
    if (l == 0) {
        int chosen[PP];
        int cnt = 0;
        for (int t = 0; t < LW; ++t) {
            int idx = ord[t];
            if (!mk[idx]) continue;
            if (cnt >= PP) break;
            bool ok = true;
            for (int s2 = 0; s2 < cnt; ++s2) {
                int d = idx - chosen[s2];
                if (d < 0) d = -d;
                if (d < 2) ok = false;
            }
            if (ok) chosen[cnt++] = idx;
        }
        int last = (cnt > 0) ? chosen[cnt - 1] : -1;
        for (int p = 0; p < PP; ++p)
            sel[b * PP + p] = (p < cnt) ? chosen[p] : last;
    }
}

// ---------------- gather selected rows of word_pe (hi+lo) ----------------------
__global__ __launch_bounds__(256) void gather_kernel(
    const __bf16* __restrict__ whi, const __bf16* __restrict__ wlo,
    const int* __restrict__ sel, float* __restrict__ x0)
{
    int g = blockIdx.x * 256 + threadIdx.x;
    int b = g >> 11;
    int p = (g >> 8) & 7;
    int c = g & 255;
    int idx = sel[b * PP + p];
    if (idx < 0) idx = 0;
    long long off = ((long long)b * LW + idx) * CC + c;
    x0[g] = (float)whi[off] + (float)wlo[off];
}

// ---------------- effective biases ---------------------------------------------
__global__ __launch_bounds__(256) void eff_bias_kernel(
    const float* __restrict__ q_b, const float* __restrict__ kv_b,
    const float* __restrict__ in_w, const float* __restrict__ in_b,
    float* __restrict__ BQE_all, float* __restrict__ bkv3)
{
    int i = blockIdx.x / 3;
    int role = blockIdx.x % 3;
    int n = threadIdx.x;
    const float* inw = in_w + (long long)i * 196608;
    const float* inb = in_b + (long long)i * 768;
    const float* srcb;
    int co;
    float* dst;
    if (role == 0)      { srcb = q_b + i * 256;        co = 0;   dst = BQE_all + i * 256; }
    else if (role == 1) { srcb = kv_b + i * 512;       co = 256; dst = bkv3 + i * 512; }
    else                { srcb = kv_b + i * 512 + 256; co = 512; dst = bkv3 + i * 512 + 256; }
    float s = inb[co + n];
    for (int k = 0; k < CC; ++k)
        s = fmaf(srcb[k], inw[(long long)k * 768 + co + n], s);
    dst[n] = s;
}

// ---------------- attention scores + softmax (block per (b,h)); KV ld=512 ------
__global__ __launch_bounds__(256) void attn_scores_kernel(
    const float* __restrict__ qp, const float* __restrict__ KV,
    const int* __restrict__ tm, float* __restrict__ attn)
{
    int b = blockIdx.x, h = blockIdx.y;
    int tid = threadIdx.x;
    __shared__ float qs[PP][DHD];
    __shared__ float sc[PP][LW];
    __shared__ float mxs[PP], sms[PP];
    {
        int q = tid >> 5, d = tid & 31;
        qs[q][d] = qp[((long long)(b * PP + q)) * CC + h * DHD + d];
    }
    __syncthreads();
    const float* kr = KV + ((long long)(b * LW + tid)) * 512 + h * DHD;
    float kreg[DHD];
#pragma unroll
    for (int j = 0; j < 8; ++j) {
        float4 f = *(const float4*)&kr[j * 4];
        kreg[j * 4 + 0] = f.x; kreg[j * 4 + 1] = f.y;
        kreg[j * 4 + 2] = f.z; kreg[j * 4 + 3] = f.w;
    }
    bool mk = tm[(long long)b * LFULL + 1 + tid] != 0;
#pragma unroll
    for (int q = 0; q < PP; ++q) {
        float s = 0.f;
#pragma unroll
        for (int d = 0; d < DHD; ++d) s = fmaf(qs[q][d], kreg[d], s);
        sc[q][tid] = mk ? s * 0.17677669529663687f : -INFINITY;
    }
    __syncthreads();
    {
        int q = tid >> 5, j = tid & 31;
        float m = -INFINITY;
        for (int kk = j; kk < LW; kk += 32) m = fmaxf(m, sc[q][kk]);
#pragma unroll
        for (int mm = 16; mm >= 1; mm >>= 1) m = fmaxf(m, __shfl_xor(m, mm, 32));
        float s = 0.f;
        for (int kk = j; kk < LW; kk += 32) s += expf(sc[q][kk] - m);
#pragma unroll
        for (int mm = 16; mm >= 1; mm >>= 1) s += __shfl_xor(s, mm, 32);
        if (j == 0) { mxs[q] = m; sms[q] = s; }
    }
    __syncthreads();
#pragma unroll
    for (int q = 0; q < PP; ++q) {
        float pv = expf(sc[q][tid] - mxs[q]) / sms[q];
        attn[(((long long)(b * NH + h)) * PP + q) * LW + tid] = pv;
    }
}

// ---------------- attn @ V (block per (b,q)); V at KV col offset 256 -----------
__global__ __launch_bounds__(256) void attn_out_kernel(
    const float* __restrict__ attn, const float* __restrict__ KV,
    float* __restrict__ aout)
{
    int b = blockIdx.x, q = blockIdx.y;
    int c = threadIdx.x, h = c >> 5;
    __shared__ float att[NH][LW];
#pragma unroll
    for (int hh = 0; hh < NH; ++hh)
        att[hh][c] = attn[(((long long)(b * NH + hh)) * PP + q) * LW + c];
    __syncthreads();
    const float* vpb = KV + ((long long)b * LW) * 512 + 256 + c;
    float acc = 0.f;
#pragma unroll 8
    for (int k = 0; k < LW; ++k)
        acc = fmaf(att[h][k], vpb[(long long)k * 512], acc);
    aout[((long long)(b * PP + q)) * CC + c] = acc;
}

// ---------------- slot_sim = mean over heads -----------------------------------
__global__ __launch_bounds__(256) void slot_sim_kernel(
    const float* __restrict__ attn, float* __restrict__ outs)
{
    int b = blockIdx.x, q = blockIdx.y, k = threadIdx.x;
    float s = 0.f;
#pragma unroll
    for (int h = 0; h < NH; ++h)
        s += attn[(((long long)(b * NH + h)) * PP + q) * LW + k];
    outs[((long long)(b * PP + q)) * LW + k] = s * 0.125f;
}

// ---------------- residual + layer norm ----------------------------------------
__global__ __launch_bounds__(256) void ln_residual_kernel(
    const float* __restrict__ xin, const float* __restrict__ add,
    const float* __restrict__ g, const float* __restrict__ bta,
    float* __restrict__ out)
{
    __shared__ float lds[4];
    int r = blockIdx.x, c = threadIdx.x;
    long long idx = (long long)r * CC + c;
    float v = xin[idx] + add[idx];
    float s = blockReduceSum(v, lds);
    float mu = s * (1.0f / (float)CC);
    float d = v - mu;
    float var = blockReduceSum(d * d, lds) * (1.0f / (float)CC);
    out[idx] = d / sqrtf(var + 1e-5f) * g[c] + bta[c];
}

// ---------------- eos broadcast -------------------------------------------------
__global__ __launch_bounds__(256) void eos_kernel(
    const float* __restrict__ eos, float* __restrict__ outp)
{
    outp[(long long)blockIdx.x * CC + threadIdx.x] = eos[threadIdx.x];
}

// =================================================================================
extern "C" void kernel_launch(void* const* d_in, const int* in_sizes, int n_in,
                              void* d_out, int out_size, void* d_ws, size_t ws_size,
                              hipStream_t stream) {
    const float* txt_emb     = (const float*)d_in[0];
    const int*   txt_mask    = (const int*)d_in[1];
    const float* video_feats = (const float*)d_in[2];
    const int*   video_mask  = (const int*)d_in[3];
    const float* word_proj_w = (const float*)d_in[4];
    const float* word_proj_b = (const float*)d_in[5];
    const float* video_proj_w = (const float*)d_in[6];
    // video_proj_b drops out (softmax shift invariance)
    const float* q_w   = (const float*)d_in[8];
    const float* q_b   = (const float*)d_in[9];
    const float* kv_w  = (const float*)d_in[10];
    const float* kv_b  = (const float*)d_in[11];
    const float* in_w  = (const float*)d_in[12];
    const float* in_b  = (const float*)d_in[13];
    const float* out_w = (const float*)d_in[14];
    const float* out_b = (const float*)d_in[15];
    const float* ln0_g = (const float*)d_in[16];
    const float* ln0_b = (const float*)d_in[17];
    const float* lin_w = (const float*)d_in[18];
    const float* lin_b = (const float*)d_in[19];
    const float* ln1_g = (const float*)d_in[20];
    const float* ln1_b = (const float*)d_in[21];
    const float* eos_slot = (const float*)d_in[22];

    // workspace layout (float units, ~120 MiB)
    float* ws = (float*)d_ws;
    __bf16* wpe_hi = (__bf16*)(ws + 0LL);          // 8388608 bf16
    __bf16* wpe_lo = (__bf16*)(ws + 4194304LL);    // 8388608 bf16
    __bf16* wp_hi  = (__bf16*)(ws + 8388608LL);
    __bf16* wp_lo  = (__bf16*)(ws + 12582912LL);
    __bf16* U_hi   = (__bf16*)(ws + 16777216LL);
    __bf16* U_lo   = (__bf16*)(ws + 20971520LL);
    float*  KV     = ws + 8388608LL;               // 32768x512 fp32 (overlaps wp/U)
    float* ent     = ws + 25165824LL;              // 32768
    int*   sel     = (int*)(ws + 25198592LL);      // 1024
    float* x0      = ws + 25199616LL;
    float* x1      = ws + 25461760LL;
    float* xmid    = ws + 25723904LL;
    float* qp      = ws + 25986048LL;
    float* attnw   = ws + 26248192LL;              // 2097152
    float* aout    = ws + 28345344LL;
    float* qatt    = ws + 28607488LL;
    float* upd     = ws + 28869632LL;
    float* WQE_all = ws + 29131776LL;              // 3*65536
    float* BQE_all = ws + 29328384LL;              // 768
    float* WT3f    = ws + 29329152LL;              // 393216 (3 layers x [512][256])
    __bf16* WT3    = (__bf16*)(ws + 29722368LL);   // 393216 bf16
    float* bkv3    = ws + 29918976LL;              // 1536
    __bf16* WPT_hi = (__bf16*)(ws + 29920512LL);   // 65536 bf16
    __bf16* WPT_lo = (__bf16*)(ws + 29953280LL);
    __bf16* VPS_hi = (__bf16*)(ws + 29986048LL);
    __bf16* VPS_lo = (__bf16*)(ws + 30018816LL);

    // transient (dead before step 3 writes the wp_hi/KV region): cums + pe table
    int*   cums  = (int*)(ws + 8388608LL);         // 32768 ints
    float* petab = ws + 8421376LL;                 // 257*256 floats

    float* outp     = (float*)d_out;
    float* out_ps   = outp;
    float* out_attn = outp + 262144LL;
    float* out_slot = outp + 33816576LL;
    float* out_eos  = outp + 34078720LL;

    // 1. word_pe (split bf16): scan + table + streaming add/split
    cumsum_kernel<<<dim3(BB), dim3(256), 0, stream>>>(txt_mask, cums);
    pe_table_kernel<<<dim3(257), dim3(256), 0, stream>>>(petab);
    word_pe2_kernel<<<dim3(8192), dim3(256), 0, stream>>>(txt_emb, cums, petab, wpe_hi, wpe_lo);
    // 2. weight preps
    split_transpose_kernel<<<dim3(256), dim3(256), 0, stream>>>(word_proj_w, WPT_hi, WPT_lo);
    split_plain_kernel<<<dim3(256), dim3(256), 0, stream>>>(video_proj_w, VPS_hi, VPS_lo);
    // 3. wp = word_pe @ Wword + b   (split x split -> split out)
    gemm_mfma<1,0,1><<<dim3(2,256,1), dim3(512), 0, stream>>>(
        wpe_hi, wpe_lo, 256, 0, WPT_hi, WPT_lo, 256, 0, word_proj_b,
        nullptr, wp_hi, wp_lo, 256, 0, 32768, 256, 256);
    // 4. U = wp @ Wvid^T            (split x split -> split out)
    gemm_mfma<1,0,1><<<dim3(2,256,1), dim3(512), 0, stream>>>(
        wp_hi, wp_lo, 256, 0, VPS_hi, VPS_lo, 256, 0, nullptr,
        nullptr, U_hi, U_lo, 256, 0, 32768, 256, 256);
    // 5. sim = U[b] @ video[b]^T    (split x fp32-in-kernel -> fp32 out_attn)
    gemm_mfma<1,1,0><<<dim3(8,2,BB), dim3(512), 0, stream>>>(
        U_hi, U_lo, 256, 65536LL, video_feats, nullptr, 256, 262144LL, nullptr,
        out_attn, nullptr, nullptr, 1024, 262144LL, 256, 1024, 256);
    // 6. softmax + entropy (in place)
    softmax_entropy_kernel<<<dim3(32768), dim3(256), 0, stream>>>(out_attn, video_mask, ent);
    // 7. selection + gather
    select_kernel<<<dim3(BB), dim3(256), 0, stream>>>(ent, txt_mask, sel);
    gather_kernel<<<dim3(1024), dim3(256), 0, stream>>>(wpe_hi, wpe_lo, sel, x0);

    // 8. folded weights (all layers, z-batched)
    gemm_f32<0,0,0><<<dim3(4,4,3), dim3(256), 0, stream>>>(
        q_w,256,65536LL, in_w,768,196608LL, nullptr, WQE_all,256,65536LL, 256,256,256);
    gemm_f32<0,0,1><<<dim3(4,4,3), dim3(256), 0, stream>>>(
        kv_w,512,131072LL, in_w+256,768,196608LL, nullptr, WT3f,256,131072LL, 256,256,256);
    gemm_f32<0,0,1><<<dim3(4,4,3), dim3(256), 0, stream>>>(
        kv_w+256,512,131072LL, in_w+512,768,196608LL, nullptr, WT3f+65536,256,131072LL, 256,256,256);
    eff_bias_kernel<<<dim3(9), dim3(256), 0, stream>>>(q_b, kv_b, in_w, in_b, BQE_all, bkv3);
    cvt_bf16_kernel<<<dim3(1536), dim3(256), 0, stream>>>(WT3f, (__bf16*)WT3);

    float* X = x0;
    for (int i = 0; i < NLAY; ++i) {
        const float* ow  = out_w + (long long)i * 65536;
        const float* ob  = out_b + (long long)i * 256;
        const float* g0  = ln0_g + (long long)i * 256;
        const float* b0  = ln0_b + (long long)i * 256;
        const float* lw  = lin_w + (long long)i * 65536;
        const float* lb  = lin_b + (long long)i * 256;
        const float* g1  = ln1_g + (long long)i * 256;
        const float* b1  = ln1_b + (long long)i * 256;

        gemm_mfma<0,0,0><<<dim3(4,256,1), dim3(512), 0, stream>>>(
            wpe_hi, nullptr, 256, 0, WT3 + (long long)i * 131072, nullptr, 256, 0,
            bkv3 + i * 512, KV, nullptr, nullptr, 512, 0, 32768, 512, 256);

        gemm_f32<0,0,0><<<dim3(4,16,1), dim3(256), 0, stream>>>(
            X,256,0, WQE_all + (long long)i*65536,256,0, BQE_all + i*256, qp,256,0, 1024,256,256);

        attn_scores_kernel<<<dim3(BB,NH), dim3(256), 0, stream>>>(qp, KV, txt_mask, attnw);
        attn_out_kernel<<<dim3(BB,PP), dim3(256), 0, stream>>>(attnw, KV, aout);
        if (i == NLAY - 1)
            slot_sim_kernel<<<dim3(BB,PP), dim3(256), 0, stream>>>(attnw, out_slot);

        gemm_f32<0,0,0><<<dim3(4,16,1), dim3(256), 0, stream>>>(
            aout,256,0, ow,256,0, ob, qatt,256,0, 1024,256,256);
        ln_residual_kernel<<<dim3(1024), dim3(256), 0, stream>>>(X, qatt, g0, b0, xmid);
        gemm_f32<0,1,0><<<dim3(4,16,1), dim3(256), 0, stream>>>(
            xmid,256,0, lw,256,0, lb, upd,256,0, 1024,256,256);
        float* Xout = (i == NLAY - 1) ? out_ps : ((X == x0) ? x1 : x0);
        ln_residual_kernel<<<dim3(1024), dim3(256), 0, stream>>>(xmid, upd, g1, b1, Xout);
        X = Xout;
    }
    eos_kernel<<<dim3(BB), dim3(256), 0, stream>>>(eos_slot, out_eos);
}

// Round 4
// 890.673 us; speedup vs baseline: 1.0273x; 1.0039x over previous
//
#include <hip/hip_runtime.h>
#include <math.h>

// Problem constants (fixed by setup_inputs)
#define BB 128
#define LFULL 257
#define LW 256     // L-1 words
#define TT 1024    // video frames
#define CC 256     // hidden
#define NH 8
#define DHD 32
#define PP 8       // NUM_PHRASE
#define NLAY 3

typedef __bf16 bf16x8 __attribute__((ext_vector_type(8)));
typedef __bf16 bf16x4 __attribute__((ext_vector_type(4)));
typedef float  f32x4  __attribute__((ext_vector_type(4)));

// ---------------- block reduce helpers (blockDim == 256 -> 4 waves) -------------
__device__ __forceinline__ float blockReduceSum(float v, volatile float* lds) {
#pragma unroll
    for (int m = 32; m >= 1; m >>= 1) v += __shfl_xor(v, m);
    __syncthreads();
    if ((threadIdx.x & 63) == 0) lds[threadIdx.x >> 6] = v;
    __syncthreads();
    return lds[0] + lds[1] + lds[2] + lds[3];
}
__device__ __forceinline__ float blockReduceMax(float v, volatile float* lds) {
#pragma unroll
    for (int m = 32; m >= 1; m >>= 1) v = fmaxf(v, __shfl_xor(v, m));
    __syncthreads();
    if ((threadIdx.x & 63) == 0) lds[threadIdx.x >> 6] = v;
    __syncthreads();
    return fmaxf(fmaxf(lds[0], lds[1]), fmaxf(lds[2], lds[3]));
}

// =================================================================================
// MFMA GEMM: C = A @ B^T (+bias).  A: M x K row-major bf16 (hi[,lo]).
// B: N x K row-major, either bf16 hi[,lo] (B_F32=0) or fp32 split in-kernel (B_F32=1).
// SPLIT=1: split-bf16 product (3 MFMAs) ~ fp32 accuracy. OUT_SPLIT=1: bf16 hi/lo out.
//
// ROUND-4 STRUCTURE: 128x128 block tile, BK=32, 512 threads = 8 waves, 64x32/wave.
// 2-PHASE DOUBLE-BUFFERED PIPELINE (r3 post-mortem): r3 showed the kernel is
// neither occupancy- (20%->39% at equal time), conflict- (8.4M vs 12.6M equal),
// compute- (MfmaUtil 18.5) nor BW-bound (37% HBM) -- it alternated load-latency
// and MFMA phases (1-phase schedule), landing at exactly 2x the 54us memory
// floor. Per K-step now: issue t+1 global loads into REGS first, ds_read+MFMA
// tile t (loads fly underneath), ds_write t+1 into the other LDS buffer, ONE
// barrier per K-step. Hazard: step t writes buf[cur^1], last read at t-1,
// protected by the barrier at top of step t.
// LDS: fragment-ordered layout (reads linear-in-lane, conflict-free), 2 buffers.
// =================================================================================

__device__ __forceinline__ int ldsoff(int row, int col) {
    // row 0..127, col 0..31, returns bf16-element offset into a 4096-elem buffer
    return ((row >> 6) << 11)
         + ((((row >> 4) & 3) << 2) + (col >> 3)) * 128
         + ((row & 15) << 3) + (col & 7);
}

template<int SPLIT, int B_F32, int OUT_SPLIT>
__global__ __launch_bounds__(512, 4) void gemm_mfma(
    const __bf16* __restrict__ Ahi, const __bf16* __restrict__ Alo, int lda, long long sA,
    const void* __restrict__ Bhp, const void* __restrict__ Blp, int ldb, long long sB,
    const float* __restrict__ bias,
    float* __restrict__ Cf, __bf16* __restrict__ Chi, __bf16* __restrict__ Clo,
    int ldc, long long sC, int M, int N, int K)
{
    __shared__ __bf16 sAh[2][4096];
    __shared__ __bf16 sAl[SPLIT ? 2 : 1][SPLIT ? 4096 : 1];
    __shared__ __bf16 sBh[2][4096];
    __shared__ __bf16 sBl[SPLIT ? 2 : 1][SPLIT ? 4096 : 1];

    const int tid = threadIdx.x;
    const int n0 = blockIdx.x * 128;
    const int m0 = blockIdx.y * 128;
    const long long bz = blockIdx.z;
    const __bf16* Ah = Ahi + bz * sA;
    const __bf16* Al = SPLIT ? (Alo + bz * sA) : nullptr;

    const int wv = tid >> 6, lane = tid & 63;
    const int wm = (wv & 1) << 6;          // 0 / 64
    const int wn = (wv >> 1) << 5;         // 0 / 32 / 64 / 96
    const int lr = lane & 15, quad = lane >> 4;

    // staging indices: 512 threads cover 128 rows x 32 cols, 8 elems each
    const int sr = tid >> 2;               // 0..127
    const int sc = (tid & 3) << 3;         // 0,8,16,24
    const int soff = ldsoff(sr, sc);
    const long long aoff = (long long)(m0 + sr) * lda + sc;
    const long long boff = (long long)(n0 + sr) * ldb + sc;

    // fragment-read bases (bf16 elems): linear in lane -> conflict-free b128 reads
    const int abase = ((wm >> 6) << 11) + (lane << 3);
    const int bbase = ((wn >> 6) << 11) + (((wn >> 4) & 3) << 9) + (lane << 3);

    // prefetch registers (one tile ahead)
    bf16x8 rAh, rAl, rBh, rBl;
    float4 rB0, rB1;

    auto LOADREGS = [&](int k0) {
        rAh = *(const bf16x8*)&Ah[aoff + k0];
        if constexpr (SPLIT) rAl = *(const bf16x8*)&Al[aoff + k0];
        if constexpr (B_F32) {
            const float* Bf = (const float*)Bhp + bz * sB;
            rB0 = *(const float4*)&Bf[boff + k0];
            rB1 = *(const float4*)&Bf[boff + k0 + 4];
        } else {
            const __bf16* Bh = (const __bf16*)Bhp + bz * sB;
            rBh = *(const bf16x8*)&Bh[boff + k0];
            if constexpr (SPLIT) {
                const __bf16* Bl = (const __bf16*)Blp + bz * sB;
                rBl = *(const bf16x8*)&Bl[boff + k0];
            }
        }
    };
    auto WRITELDS = [&](int buf) {
        *(bf16x8*)&sAh[buf][soff] = rAh;
        if constexpr (SPLIT) *(bf16x8*)&sAl[buf][soff] = rAl;
        if constexpr (B_F32) {
            bf16x8 h8, l8;
            h8[0] = (__bf16)rB0.x; l8[0] = (__bf16)(rB0.x - (float)h8[0]);
            h8[1] = (__bf16)rB0.y; l8[1] = (__bf16)(rB0.y - (float)h8[1]);
            h8[2] = (__bf16)rB0.z; l8[2] = (__bf16)(rB0.z - (float)h8[2]);
            h8[3] = (__bf16)rB0.w; l8[3] = (__bf16)(rB0.w - (float)h8[3]);
            h8[4] = (__bf16)rB1.x; l8[4] = (__bf16)(rB1.x - (float)h8[4]);
            h8[5] = (__bf16)rB1.y; l8[5] = (__bf16)(rB1.y - (float)h8[5]);
            h8[6] = (__bf16)rB1.z; l8[6] = (__bf16)(rB1.z - (float)h8[6]);
            h8[7] = (__bf16)rB1.w; l8[7] = (__bf16)(rB1.w - (float)h8[7]);
            *(bf16x8*)&sBh[buf][soff] = h8;
            *(bf16x8*)&sBl[buf][soff] = l8;
        } else {
            *(bf16x8*)&sBh[buf][soff] = rBh;
            if constexpr (SPLIT) *(bf16x8*)&sBl[buf][soff] = rBl;
        }
    };

    f32x4 acc[4][2];
#pragma unroll
    for (int i = 0; i < 4; ++i)
#pragma unroll
        for (int j = 0; j < 2; ++j) acc[i][j] = (f32x4)(0.f);

    const int nt = K >> 5;
    LOADREGS(0);
    WRITELDS(0);
    int cur = 0;
    for (int t = 0; t < nt; ++t) {
        __syncthreads();                      // buf[cur] writes visible; prior reads done
        if (t + 1 < nt) LOADREGS((t + 1) << 5);   // issue next-tile loads early

        // ---- fragments + MFMA from buf[cur] ----
        bf16x8 fah[4], fbh[2];
        bf16x8 fal[4], fbl[2];
#pragma unroll
        for (int i = 0; i < 4; ++i) {
            fah[i] = *(const bf16x8*)&sAh[cur][abase + i * 512];
            if constexpr (SPLIT)
                fal[i] = *(const bf16x8*)&sAl[cur][abase + i * 512];
        }
#pragma unroll
        for (int j = 0; j < 2; ++j) {
            fbh[j] = *(const bf16x8*)&sBh[cur][bbase + j * 512];
            if constexpr (SPLIT)
                fbl[j] = *(const bf16x8*)&sBl[cur][bbase + j * 512];
        }
#pragma unroll
        for (int i = 0; i < 4; ++i)
#pragma unroll
            for (int j = 0; j < 2; ++j) {
                if constexpr (SPLIT) {
                    acc[i][j] = __builtin_amdgcn_mfma_f32_16x16x32_bf16(fal[i], fbh[j], acc[i][j], 0, 0, 0);
                    acc[i][j] = __builtin_amdgcn_mfma_f32_16x16x32_bf16(fah[i], fbl[j], acc[i][j], 0, 0, 0);
                }
                acc[i][j] = __builtin_amdgcn_mfma_f32_16x16x32_bf16(fah[i], fbh[j], acc[i][j], 0, 0, 0);
            }

        if (t + 1 < nt) WRITELDS(cur ^ 1);    // other buffer: safe, readers synced at top
        cur ^= 1;
    }

    // ---- epilogue: C[row][col], col = lane&15, row = quad*4 + r (m89-verified) ----
#pragma unroll
    for (int i = 0; i < 4; ++i)
#pragma unroll
        for (int j = 0; j < 2; ++j) {
            int col = n0 + wn + j * 16 + lr;
            int row0 = m0 + wm + i * 16 + quad * 4;
            float bv = bias ? bias[col] : 0.f;
#pragma unroll
            for (int r = 0; r < 4; ++r) {
                float v = acc[i][j][r] + bv;
                long long off = (long long)(row0 + r) * ldc + col + bz * sC;
                if constexpr (OUT_SPLIT) {
                    __bf16 h = (__bf16)v;
                    Chi[off] = h;
                    Clo[off] = (__bf16)(v - (float)h);
                } else {
                    Cf[off] = v;
                }
            }
        }
}

// ---------------- fp32 tiled GEMM (small/fold/residual gemms) -------------------
#define GTS 64
#define GKT 16
#define GPAD 68

template<int TRANSB, int RELU, int TRANSC>
__global__ __launch_bounds__(256) void gemm_f32(
    const float* __restrict__ A, int lda, long long sA,
    const float* __restrict__ Bm, int ldb, long long sB,
    const float* __restrict__ bias,
    float* __restrict__ C, int ldc, long long sC,
    int M, int N, int K)
{
    __shared__ float As[GKT][GPAD];
    __shared__ float Bs[GKT][GPAD];
    const int tid = threadIdx.x;
    const int tx = tid & 15, ty = tid >> 4;
    const int n0 = blockIdx.x * GTS;
    const int m0 = blockIdx.y * GTS;
    const long long bz = blockIdx.z;
    const float* Ab = A + bz * sA;
    const float* Bb = Bm + bz * sB;
    float* Cb = C + bz * sC;

    const int lr = tid >> 2;
    const int lc = (tid & 3) << 2;
    const int br = tid >> 4;
    const int bc = (tid & 15) << 2;

    float acc[4][4] = {};

    for (int k0 = 0; k0 < K; k0 += GKT) {
        float4 a = *(const float4*)&Ab[(long long)(m0 + lr) * lda + k0 + lc];
        As[lc + 0][lr] = a.x; As[lc + 1][lr] = a.y;
        As[lc + 2][lr] = a.z; As[lc + 3][lr] = a.w;
        if (TRANSB) {
            float4 b = *(const float4*)&Bb[(long long)(n0 + lr) * ldb + k0 + lc];
            Bs[lc + 0][lr] = b.x; Bs[lc + 1][lr] = b.y;
            Bs[lc + 2][lr] = b.z; Bs[lc + 3][lr] = b.w;
        } else {
            float4 b = *(const float4*)&Bb[(long long)(k0 + br) * ldb + n0 + bc];
            *(float4*)&Bs[br][bc] = b;
        }
        __syncthreads();
#pragma unroll
        for (int k = 0; k < GKT; ++k) {
            float4 av = *(const float4*)&As[k][ty << 2];
            float4 bv = *(const float4*)&Bs[k][tx << 2];
            float ar[4] = {av.x, av.y, av.z, av.w};
            float brr[4] = {bv.x, bv.y, bv.z, bv.w};
#pragma unroll
            for (int i = 0; i < 4; ++i)
#pragma unroll
                for (int j = 0; j < 4; ++j)
                    acc[i][j] = fmaf(ar[i], brr[j], acc[i][j]);
        }
        __syncthreads();
    }

    float bbr[4] = {0.f, 0.f, 0.f, 0.f};
    if (bias) {
        float4 bb = *(const float4*)&bias[n0 + (tx << 2)];
        bbr[0] = bb.x; bbr[1] = bb.y; bbr[2] = bb.z; bbr[3] = bb.w;
    }
#pragma unroll
    for (int i = 0; i < 4; ++i) {
#pragma unroll
        for (int j = 0; j < 4; ++j) {
            float o = acc[i][j] + bbr[j];
            if (RELU) o = fmaxf(o, 0.f);
            if (TRANSC)
                Cb[(long long)(n0 + (tx << 2) + j) * ldc + m0 + (ty << 2) + i] = o;
            else
                Cb[(long long)(m0 + (ty << 2) + i) * ldc + n0 + (tx << 2) + j] = o;
        }
    }
}

// ---------------- word_pe: scan + table + streaming add/split -------------------
// pe depends only on (count, c); count = cumsum(mask) is an integer in [0,256]
// -> precompute a 257x256 table (bit-identical powf/sinf/cosf), then stream.

__global__ __launch_bounds__(256) void cumsum_kernel(
    const int* __restrict__ tm, int* __restrict__ cums)
{
    int b = blockIdx.x, c = threadIdx.x;
    int lane = c & 63;
    int v = (tm[(long long)b * LFULL + 1 + c] != 0) ? 1 : 0;
#pragma unroll
    for (int off = 1; off < 64; off <<= 1) {
        int t = __shfl_up(v, off);
        if (lane >= off) v += t;
    }
    __shared__ int wsum[4];
    if (lane == 63) wsum[c >> 6] = v;
    __syncthreads();
    int w = c >> 6, add = 0;
    for (int i = 0; i < w; ++i) add += wsum[i];
    cums[b * LW + c] = v + add;
}

__global__ __launch_bounds__(256) void pe_table_kernel(float* __restrict__ petab)
{
    int n = blockIdx.x;          // count value 0..256
    int c = threadIdx.x;
    int i2 = c & ~1;
    float freq = powf(10000.0f, (float)i2 / (float)CC);
    float arg = (float)n / freq;
    petab[n * CC + c] = (c & 1) ? cosf(arg) : sinf(arg);
}

__global__ __launch_bounds__(256) void word_pe2_kernel(
    const float* __restrict__ te, const int* __restrict__ cums,
    const float* __restrict__ petab,
    __bf16* __restrict__ whi, __bf16* __restrict__ wlo)
{
    int g = blockIdx.x * 256 + threadIdx.x;   // 0 .. 128*256*64-1
    int c0 = (g & 63) << 2;                   // channel base (float4)
    int l  = (g >> 6) & 255;
    int b  = g >> 14;
    int cnt = cums[b * LW + l];
    float4 s = *(const float4*)&te[((long long)(b * LFULL + 1 + l)) * CC + c0];
    float4 p = *(const float4*)&petab[cnt * CC + c0];
    float v0 = s.x + p.x, v1 = s.y + p.y, v2 = s.z + p.z, v3 = s.w + p.w;
    bf16x4 h, lo;
    h[0] = (__bf16)v0; lo[0] = (__bf16)(v0 - (float)h[0]);
    h[1] = (__bf16)v1; lo[1] = (__bf16)(v1 - (float)h[1]);
    h[2] = (__bf16)v2; lo[2] = (__bf16)(v2 - (float)h[2]);
    h[3] = (__bf16)v3; lo[3] = (__bf16)(v3 - (float)h[3]);
    long long o = ((long long)(b * LW + l)) * CC + c0;
    *(bf16x4*)&whi[o] = h;
    *(bf16x4*)&wlo[o] = lo;
}

// ---------------- weight prep -------------------------------------------------
__global__ __launch_bounds__(256) void split_transpose_kernel(
    const float* __restrict__ W, __bf16* __restrict__ hi, __bf16* __restrict__ lo)
{
    int n = blockIdx.x, k = threadIdx.x;
    float v = W[(long long)k * CC + n];
    __bf16 h = (__bf16)v;
    hi[(long long)n * CC + k] = h;
    lo[(long long)n * CC + k] = (__bf16)(v - (float)h);
}
__global__ __launch_bounds__(256) void split_plain_kernel(
    const float* __restrict__ W, __bf16* __restrict__ hi, __bf16* __restrict__ lo)
{
    int g = blockIdx.x * 256 + threadIdx.x;
    float v = W[g];
    __bf16 h = (__bf16)v;
    hi[g] = h;
    lo[g] = (__bf16)(v - (float)h);
}
__global__ __launch_bounds__(256) void cvt_bf16_kernel(
    const float* __restrict__ src, __bf16* __restrict__ dst)
{
    int g = blockIdx.x * 256 + threadIdx.x;
    dst[g] = (__bf16)src[g];
}

// ---------------- in-place softmax over T + entropy ----------------------------
__global__ __launch_bounds__(256) void softmax_entropy_kernel(
    float* __restrict__ attn, const int* __restrict__ vmask,
    float* __restrict__ ent)
{
    __shared__ float lds[4];
    long long row = blockIdx.x;
    int b = blockIdx.x >> 8;
    float* p = attn + row * TT;
    const int* m = vmask + (long long)b * TT;
    int t4 = threadIdx.x * 4;
    float4 v = *(const float4*)&p[t4];
    int4 mm4 = *(const int4*)&m[t4];
    float x[4];
    x[0] = mm4.x ? v.x : -INFINITY;
    x[1] = mm4.y ? v.y : -INFINITY;
    x[2] = mm4.z ? v.z : -INFINITY;
    x[3] = mm4.w ? v.w : -INFINITY;
    float mx = fmaxf(fmaxf(x[0], x[1]), fmaxf(x[2], x[3]));
    mx = blockReduceMax(mx, lds);
    float e[4];
    float ps = 0.f;
#pragma unroll
    for (int j = 0; j < 4; ++j) { e[j] = expf(x[j] - mx); ps += e[j]; }
    float sum = blockReduceSum(ps, lds);
    float q[4];
    float ce = 0.f;
#pragma unroll
    for (int j = 0; j < 4; ++j) {
        q[j] = e[j] / sum;
        ce += q[j] * logf(q[j] + 1e-6f);
    }
    ce = blockReduceSum(ce, lds);
    *(float4*)&p[t4] = make_float4(q[0], q[1], q[2], q[3]);
    if (threadIdx.x == 0) ent[row] = -ce;
}

// ---------------- greedy selection ---------------------------------------------
__global__ __launch_bounds__(256) void select_kernel(
    const float* __restrict__ ent, const int* __restrict__ tm,
    int* __restrict__ sel)
{
    int b = blockIdx.x;
    int l = threadIdx.x;
    __shared__ float sc[LW];
    __shared__ int ord[LW];
    __shared__ unsigned char mk[LW];
    mk[l] = (tm[(long long)b * LFULL + 1 + l] != 0);
    sc[l] = mk[l] ? ent[(long long)b * LW + l] : -INFINITY;
    __syncthreads();
    float mys = sc[l];
    int r = 0;
    for (int j = 0; j < LW; ++j) {
        float s = sc[j];
        r += (s > mys) || (s == mys && j < l);
    }
    ord[r] = l;
    __syncthreads();
    if (l == 0) {
        int chosen[PP];
        int cnt = 0;
        for (int t = 0; t < LW; ++t) {
            int idx = ord[t];
            if (!mk[idx]) continue;
            if (cnt >= PP) break;
            bool ok = true;
            for (int s2 = 0; s2 < cnt; ++s2) {
                int d = idx - chosen[s2];
                if (d < 0) d = -d;
                if (d < 2) ok = false;
            }
            if (ok) chosen[cnt++] = idx;
        }
        int last = (cnt > 0) ? chosen[cnt - 1] : -1;
        for (int p = 0; p < PP; ++p)
            sel[b * PP + p] = (p < cnt) ? chosen[p] : last;
    }
}

// ---------------- gather selected rows of word_pe (hi+lo) ----------------------
__global__ __launch_bounds__(256) void gather_kernel(
    const __bf16* __restrict__ whi, const __bf16* __restrict__ wlo,
    const int* __restrict__ sel, float* __restrict__ x0)
{
    int g = blockIdx.x * 256 + threadIdx.x;
    int b = g >> 11;
    int p = (g >> 8) & 7;
    int c = g & 255;
    int idx = sel[b * PP + p];
    if (idx < 0) idx = 0;
    long long off = ((long long)b * LW + idx) * CC + c;
    x0[g] = (float)whi[off] + (float)wlo[off];
}

// ---------------- effective biases ---------------------------------------------
__global__ __launch_bounds__(256) void eff_bias_kernel(
    const float* __restrict__ q_b, const float* __restrict__ kv_b,
    const float* __restrict__ in_w, const float* __restrict__ in_b,
    float* __restrict__ BQE_all, float* __restrict__ bkv3)
{
    int i = blockIdx.x / 3;
    int role = blockIdx.x % 3;
    int n = threadIdx.x;
    const float* inw = in_w + (long long)i * 196608;
    const float* inb = in_b + (long long)i * 768;
    const float* srcb;
    int co;
    float* dst;
    if (role == 0)      { srcb = q_b + i * 256;        co = 0;   dst = BQE_all + i * 256; }
    else if (role == 1) { srcb = kv_b + i * 512;       co = 256; dst = bkv3 + i * 512; }
    else                { srcb = kv_b + i * 512 + 256; co = 512; dst = bkv3 + i * 512 + 256; }
    float s = inb[co + n];
    for (int k = 0; k < CC; ++k)
        s = fmaf(srcb[k], inw[(long long)k * 768 + co + n], s);
    dst[n] = s;
}

// ---------------- attention scores + softmax (block per (b,h)); KV ld=512 ------
__global__ __launch_bounds__(256) void attn_scores_kernel(
    const float* __restrict__ qp, const float* __restrict__ KV,
    const int* __restrict__ tm, float* __restrict__ attn)
{
    int b = blockIdx.x, h = blockIdx.y;
    int tid = threadIdx.x;
    __shared__ float qs[PP][DHD];
    __shared__ float sc[PP][LW];
    __shared__ float mxs[PP], sms[PP];
    {
        int q = tid >> 5, d = tid & 31;
        qs[q][d] = qp[((long long)(b * PP + q)) * CC + h * DHD + d];
    }
    __syncthreads();
    const float* kr = KV + ((long long)(b * LW + tid)) * 512 + h * DHD;
    float kreg[DHD];
#pragma unroll
    for (int j = 0; j < 8; ++j) {
        float4 f = *(const float4*)&kr[j * 4];
        kreg[j * 4 + 0] = f.x; kreg[j * 4 + 1] = f.y;
        kreg[j * 4 + 2] = f.z; kreg[j * 4 + 3] = f.w;
    }
    bool mk = tm[(long long)b * LFULL + 1 + tid] != 0;
#pragma unroll
    for (int q = 0; q < PP; ++q) {
        float s = 0.f;
#pragma unroll
        for (int d = 0; d < DHD; ++d) s = fmaf(qs[q][d], kreg[d], s);
        sc[q][tid] = mk ? s * 0.17677669529663687f : -INFINITY;
    }
    __syncthreads();
    {
        int q = tid >> 5, j = tid & 31;
        float m = -INFINITY;
        for (int kk = j; kk < LW; kk += 32) m = fmaxf(m, sc[q][kk]);
#pragma unroll
        for (int mm = 16; mm >= 1; mm >>= 1) m = fmaxf(m, __shfl_xor(m, mm, 32));
        float s = 0.f;
        for (int kk = j; kk < LW; kk += 32) s += expf(sc[q][kk] - m);
#pragma unroll
        for (int mm = 16; mm >= 1; mm >>= 1) s += __shfl_xor(s, mm, 32);
        if (j == 0) { mxs[q] = m; sms[q] = s; }
    }
    __syncthreads();
#pragma unroll
    for (int q = 0; q < PP; ++q) {
        float pv = expf(sc[q][tid] - mxs[q]) / sms[q];
        attn[(((long long)(b * NH + h)) * PP + q) * LW + tid] = pv;
    }
}

// ---------------- attn @ V (block per (b,q)); V at KV col offset 256 -----------
__global__ __launch_bounds__(256) void attn_out_kernel(
    const float* __restrict__ attn, const float* __restrict__ KV,
    float* __restrict__ aout)
{
    int b = blockIdx.x, q = blockIdx.y;
    int c = threadIdx.x, h = c >> 5;
    __shared__ float att[NH][LW];
#pragma unroll
    for (int hh = 0; hh < NH; ++hh)
        att[hh][c] = attn[(((long long)(b * NH + hh)) * PP + q) * LW + c];
    __syncthreads();
    const float* vpb = KV + ((long long)b * LW) * 512 + 256 + c;
    float acc = 0.f;
#pragma unroll 8
    for (int k = 0; k < LW; ++k)
        acc = fmaf(att[h][k], vpb[(long long)k * 512], acc);
    aout[((long long)(b * PP + q)) * CC + c] = acc;
}

// ---------------- slot_sim = mean over heads -----------------------------------
__global__ __launch_bounds__(256) void slot_sim_kernel(
    const float* __restrict__ attn, float* __restrict__ outs)
{
    int b = blockIdx.x, q = blockIdx.y, k = threadIdx.x;
    float s = 0.f;
#pragma unroll
    for (int h = 0; h < NH; ++h)
        s += attn[(((long long)(b * NH + h)) * PP + q) * LW + k];
    outs[((long long)(b * PP + q)) * LW + k] = s * 0.125f;
}

// ---------------- residual + layer norm ----------------------------------------
__global__ __launch_bounds__(256) void ln_residual_kernel(
    const float* __restrict__ xin, const float* __restrict__ add,
    const float* __restrict__ g, const float* __restrict__ bta,
    float* __restrict__ out)
{
    __shared__ float lds[4];
    int r = blockIdx.x, c = threadIdx.x;
    long long idx = (long long)r * CC + c;
    float v = xin[idx] + add[idx];
    float s = blockReduceSum(v, lds);
    float mu = s * (1.0f / (float)CC);
    float d = v - mu;
    float var = blockReduceSum(d * d, lds) * (1.0f / (float)CC);
    out[idx] = d / sqrtf(var + 1e-5f) * g[c] + bta[c];
}

// ---------------- eos broadcast -------------------------------------------------
__global__ __launch_bounds__(256) void eos_kernel(
    const float* __restrict__ eos, float* __restrict__ outp)
{
    outp[(long long)blockIdx.x * CC + threadIdx.x] = eos[threadIdx.x];
}

// =================================================================================
extern "C" void kernel_launch(void* const* d_in, const int* in_sizes, int n_in,
                              void* d_out, int out_size, void* d_ws, size_t ws_size,
                              hipStream_t stream) {
    const float* txt_emb     = (const float*)d_in[0];
    const int*   txt_mask    = (const int*)d_in[1];
    const float* video_feats = (const float*)d_in[2];
    const int*   video_mask  = (const int*)d_in[3];
    const float* word_proj_w = (const float*)d_in[4];
    const float* word_proj_b = (const float*)d_in[5];
    const float* video_proj_w = (const float*)d_in[6];
    // video_proj_b drops out (softmax shift invariance)
    const float* q_w   = (const float*)d_in[8];
    const float* q_b   = (const float*)d_in[9];
    const float* kv_w  = (const float*)d_in[10];
    const float* kv_b  = (const float*)d_in[11];
    const float* in_w  = (const float*)d_in[12];
    const float* in_b  = (const float*)d_in[13];
    const float* out_w = (const float*)d_in[14];
    const float* out_b = (const float*)d_in[15];
    const float* ln0_g = (const float*)d_in[16];
    const float* ln0_b = (const float*)d_in[17];
    const float* lin_w = (const float*)d_in[18];
    const float* lin_b = (const float*)d_in[19];
    const float* ln1_g = (const float*)d_in[20];
    const float* ln1_b = (const float*)d_in[21];
    const float* eos_slot = (const float*)d_in[22];

    // workspace layout (float units, ~120 MiB)
    float* ws = (float*)d_ws;
    __bf16* wpe_hi = (__bf16*)(ws + 0LL);          // 8388608 bf16
    __bf16* wpe_lo = (__bf16*)(ws + 4194304LL);    // 8388608 bf16
    __bf16* wp_hi  = (__bf16*)(ws + 8388608LL);
    __bf16* wp_lo  = (__bf16*)(ws + 12582912LL);
    __bf16* U_hi   = (__bf16*)(ws + 16777216LL);
    __bf16* U_lo   = (__bf16*)(ws + 20971520LL);
    float*  KV     = ws + 8388608LL;               // 32768x512 fp32 (overlaps wp/U)
    float* ent     = ws + 25165824LL;              // 32768
    int*   sel     = (int*)(ws + 25198592LL);      // 1024
    float* x0      = ws + 25199616LL;
    float* x1      = ws + 25461760LL;
    float* xmid    = ws + 25723904LL;
    float* qp      = ws + 25986048LL;
    float* attnw   = ws + 26248192LL;              // 2097152
    float* aout    = ws + 28345344LL;
    float* qatt    = ws + 28607488LL;
    float* upd     = ws + 28869632LL;
    float* WQE_all = ws + 29131776LL;              // 3*65536
    float* BQE_all = ws + 29328384LL;              // 768
    float* WT3f    = ws + 29329152LL;              // 393216 (3 layers x [512][256])
    __bf16* WT3    = (__bf16*)(ws + 29722368LL);   // 393216 bf16
    float* bkv3    = ws + 29918976LL;              // 1536
    __bf16* WPT_hi = (__bf16*)(ws + 29920512LL);   // 65536 bf16
    __bf16* WPT_lo = (__bf16*)(ws + 29953280LL);
    __bf16* VPS_hi = (__bf16*)(ws + 29986048LL);
    __bf16* VPS_lo = (__bf16*)(ws + 30018816LL);

    // transient (dead before step 3 writes the wp_hi/KV region): cums + pe table
    int*   cums  = (int*)(ws + 8388608LL);         // 32768 ints
    float* petab = ws + 8421376LL;                 // 257*256 floats

    float* outp     = (float*)d_out;
    float* out_ps   = outp;
    float* out_attn = outp + 262144LL;
    float* out_slot = outp + 33816576LL;
    float* out_eos  = outp + 34078720LL;

    // 1. word_pe (split bf16): scan + table + streaming add/split
    cumsum_kernel<<<dim3(BB), dim3(256), 0, stream>>>(txt_mask, cums);
    pe_table_kernel<<<dim3(257), dim3(256), 0, stream>>>(petab);
    word_pe2_kernel<<<dim3(8192), dim3(256), 0, stream>>>(txt_emb, cums, petab, wpe_hi, wpe_lo);
    // 2. weight preps
    split_transpose_kernel<<<dim3(256), dim3(256), 0, stream>>>(word_proj_w, WPT_hi, WPT_lo);
    split_plain_kernel<<<dim3(256), dim3(256), 0, stream>>>(video_proj_w, VPS_hi, VPS_lo);
    // 3. wp = word_pe @ Wword + b   (split x split -> split out)
    gemm_mfma<1,0,1><<<dim3(2,256,1), dim3(512), 0, stream>>>(
        wpe_hi, wpe_lo, 256, 0, WPT_hi, WPT_lo, 256, 0, word_proj_b,
        nullptr, wp_hi, wp_lo, 256, 0, 32768, 256, 256);
    // 4. U = wp @ Wvid^T            (split x split -> split out)
    gemm_mfma<1,0,1><<<dim3(2,256,1), dim3(512), 0, stream>>>(
        wp_hi, wp_lo, 256, 0, VPS_hi, VPS_lo, 256, 0, nullptr,
        nullptr, U_hi, U_lo, 256, 0, 32768, 256, 256);
    // 5. sim = U[b] @ video[b]^T    (split x fp32-in-kernel -> fp32 out_attn)
    gemm_mfma<1,1,0><<<dim3(8,2,BB), dim3(512), 0, stream>>>(
        U_hi, U_lo, 256, 65536LL, video_feats, nullptr, 256, 262144LL, nullptr,
        out_attn, nullptr, nullptr, 1024, 262144LL, 256, 1024, 256);
    // 6. softmax + entropy (in place)
    softmax_entropy_kernel<<<dim3(32768), dim3(256), 0, stream>>>(out_attn, video_mask, ent);
    // 7. selection + gather
    select_kernel<<<dim3(BB), dim3(256), 0, stream>>>(ent, txt_mask, sel);
    gather_kernel<<<dim3(1024), dim3(256), 0, stream>>>(wpe_hi, wpe_lo, sel, x0);

    // 8. folded weights (all layers, z-batched)
    gemm_f32<0,0,0><<<dim3(4,4,3), dim3(256), 0, stream>>>(
        q_w,256,65536LL, in_w,768,196608LL, nullptr, WQE_all,256,65536LL, 256,256,256);
    gemm_f32<0,0,1><<<dim3(4,4,3), dim3(256), 0, stream>>>(
        kv_w,512,131072LL, in_w+256,768,196608LL, nullptr, WT3f,256,131072LL, 256,256,256);
    gemm_f32<0,0,1><<<dim3(4,4,3), dim3(256), 0, stream>>>(
        kv_w+256,512,131072LL, in_w+512,768,196608LL, nullptr, WT3f+65536,256,131072LL, 256,256,256);
    eff_bias_kernel<<<dim3(9), dim3(256), 0, stream>>>(q_b, kv_b, in_w, in_b, BQE_all, bkv3);
    cvt_bf16_kernel<<<dim3(1536), dim3(256), 0, stream>>>(WT3f, (__bf16*)WT3);

    float* X = x0;
    for (int i = 0; i < NLAY; ++i) {
        const float* ow  = out_w + (long long)i * 65536;
        const float* ob  = out_b + (long long)i * 256;
        const float* g0  = ln0_g + (long long)i * 256;
        const float* b0  = ln0_b + (long long)i * 256;
        const float* lw  = lin_w + (long long)i * 65536;
        const float* lb  = lin_b + (long long)i * 256;
        const float* g1  = ln1_g + (long long)i * 256;
        const float* b1  = ln1_b + (long long)i * 256;

        gemm_mfma<0,0,0><<<dim3(4,256,1), dim3(512), 0, stream>>>(
            wpe_hi, nullptr, 256, 0, WT3 + (long long)i * 131072, nullptr, 256, 0,
            bkv3 + i * 512, KV, nullptr, nullptr, 512, 0, 32768, 512, 256);

        gemm_f32<0,0,0><<<dim3(4,16,1), dim3(256), 0, stream>>>(
            X,256,0, WQE_all + (long long)i*65536,256,0, BQE_all + i*256, qp,256,0, 1024,256,256);

        attn_scores_kernel<<<dim3(BB,NH), dim3(256), 0, stream>>>(qp, KV, txt_mask, attnw);
        attn_out_kernel<<<dim3(BB,PP), dim3(256), 0, stream>>>(attnw, KV, aout);
        if (i == NLAY - 1)
            slot_sim_kernel<<<dim3(BB,PP), dim3(256), 0, stream>>>(attnw, out_slot);

        gemm_f32<0,0,0><<<dim3(4,16,1), dim3(256), 0, stream>>>(
            aout,256,0, ow,256,0, ob, qatt,256,0, 1024,256,256);
        ln_residual_kernel<<<dim3(1024), dim3(256), 0, stream>>>(X, qatt, g0, b0, xmid);
        gemm_f32<0,1,0><<<dim3(4,16,1), dim3(256), 0, stream>>>(
            xmid,256,0, lw,256,0, lb, upd,256,0, 1024,256,256);
        float* Xout = (i == NLAY - 1) ? out_ps : ((X == x0) ? x1 : x0);
        ln_residual_kernel<<<dim3(1024), dim3(256), 0, stream>>>(xmid, upd, g1, b1, Xout);
        X = Xout;
    }
    eos_kernel<<<dim3(BB), dim3(256), 0, stream>>>(eos_slot, out_eos);
}

// Round 6
// 889.908 us; speedup vs baseline: 1.0281x; 1.0009x over previous
//
#include <hip/hip_runtime.h>
#include <math.h>

// Problem constants (fixed by setup_inputs)
#define BB 128
#define LFULL 257
#define LW 256     // L-1 words
#define TT 1024    // video frames
#define CC 256     // hidden
#define NH 8
#define DHD 32
#define PP 8       // NUM_PHRASE
#define NLAY 3

typedef __bf16 bf16x8 __attribute__((ext_vector_type(8)));
typedef __bf16 bf16x4 __attribute__((ext_vector_type(4)));
typedef float  f32x4  __attribute__((ext_vector_type(4)));

// ---------------- block reduce helpers (blockDim == 256 -> 4 waves) -------------
__device__ __forceinline__ float blockReduceSum(float v, volatile float* lds) {
#pragma unroll
    for (int m = 32; m >= 1; m >>= 1) v += __shfl_xor(v, m);
    __syncthreads();
    if ((threadIdx.x & 63) == 0) lds[threadIdx.x >> 6] = v;
    __syncthreads();
    return lds[0] + lds[1] + lds[2] + lds[3];
}
__device__ __forceinline__ float blockReduceMax(float v, volatile float* lds) {
#pragma unroll
    for (int m = 32; m >= 1; m >>= 1) v = fmaxf(v, __shfl_xor(v, m));
    __syncthreads();
    if ((threadIdx.x & 63) == 0) lds[threadIdx.x >> 6] = v;
    __syncthreads();
    return fmaxf(fmaxf(lds[0], lds[1]), fmaxf(lds[2], lds[3]));
}

// =================================================================================
// MFMA GEMM: C = A @ B^T (+bias).  A: M x K row-major bf16 (hi[,lo]).
// B: N x K row-major, either bf16 hi[,lo] (B_F32=0) or fp32 split in-kernel (B_F32=1).
// SPLIT=1: split-bf16 product (3 MFMAs) ~ fp32 accuracy. OUT_SPLIT=1: bf16 hi/lo out.
//
// ROUND-6 = ROUND-5 with the macro token-pasting bug fixed (rB##S##0.x lexed
// 0.x as one pp-number -> invalid paste; float4 regs renamed rBa0/rBb0/rBa1/rBb1
// so the paste ends before the member access).
//
// DEPTH-2 PREFETCH PIPELINE (r4 post-mortem): the r4 2-phase schedule covered the
// HBM load latency (~900 cyc, m126) with only one MFMA block (~150-200 cyc) --
// loads issued at iter t were consumed by ds_write at the SAME iter's end, so
// every wave stalled ~700 cyc at the vmcnt wait (sim stuck at 108us, 39% HBM,
// 19% MfmaUtil, insensitive to occupancy/conflicts). Now: TWO register sets,
// parity static via 2x-unrolled K-loop (rule #20: no runtime-indexed reg arrays).
// Tile k lives in regset k&1; loads issued at iter t are written at iter t+2
// (~2 iterations of cover). One barrier per K-step.
//   prologue: R0<-t0; R1<-t1; R0->lds0; R0<-t2; barrier
//   even t:   MFMA(lds0); R1(t+1)->lds1; R1<-t+3; barrier
//   odd  t+1: MFMA(lds1); R0(t+2)->lds0; R0<-t+4; barrier
// Hazard: write to lds[b] at iter t targets the buffer last READ at iter t-1;
// the barrier at end of t-1 (with compiler lgkmcnt drain) orders read-then-write.
// LDS: fragment-ordered layout (reads linear-in-lane, conflict-free), 2 buffers.
// =================================================================================

__device__ __forceinline__ int ldsoff(int row, int col) {
    // row 0..127, col 0..31, returns bf16-element offset into a 4096-elem buffer
    return ((row >> 6) << 11)
         + ((((row >> 4) & 3) << 2) + (col >> 3)) * 128
         + ((row & 15) << 3) + (col & 7);
}

template<int SPLIT, int B_F32, int OUT_SPLIT>
__global__ __launch_bounds__(512, 4) void gemm_mfma(
    const __bf16* __restrict__ Ahi, const __bf16* __restrict__ Alo, int lda, long long sA,
    const void* __restrict__ Bhp, const void* __restrict__ Blp, int ldb, long long sB,
    const float* __restrict__ bias,
    float* __restrict__ Cf, __bf16* __restrict__ Chi, __bf16* __restrict__ Clo,
    int ldc, long long sC, int M, int N, int K)
{
    __shared__ __bf16 sAh[2][4096];
    __shared__ __bf16 sAl[SPLIT ? 2 : 1][SPLIT ? 4096 : 1];
    __shared__ __bf16 sBh[2][4096];
    __shared__ __bf16 sBl[SPLIT ? 2 : 1][SPLIT ? 4096 : 1];

    const int tid = threadIdx.x;
    const int n0 = blockIdx.x * 128;
    const int m0 = blockIdx.y * 128;
    const long long bz = blockIdx.z;
    const __bf16* Ah = Ahi + bz * sA;
    const __bf16* Al = SPLIT ? (Alo + bz * sA) : nullptr;

    const int wv = tid >> 6, lane = tid & 63;
    const int wm = (wv & 1) << 6;          // 0 / 64
    const int wn = (wv >> 1) << 5;         // 0 / 32 / 64 / 96
    const int lr = lane & 15, quad = lane >> 4;

    // staging indices: 512 threads cover 128 rows x 32 cols, 8 elems each
    const int sr = tid >> 2;               // 0..127
    const int sc = (tid & 3) << 3;         // 0,8,16,24
    const int soff = ldsoff(sr, sc);
    const long long aoff = (long long)(m0 + sr) * lda + sc;
    const long long boff = (long long)(n0 + sr) * ldb + sc;

    // fragment-read bases (bf16 elems): linear in lane -> conflict-free b128 reads
    const int abase = ((wm >> 6) << 11) + (lane << 3);
    const int bbase = ((wn >> 6) << 11) + (((wn >> 4) & 3) << 9) + (lane << 3);

    // two prefetch register sets (tile k -> set k&1)
    bf16x8 rAh0, rAl0, rBh0, rBl0; float4 rBa0, rBb0;
    bf16x8 rAh1, rAl1, rBh1, rBl1; float4 rBa1, rBb1;

#define LOADR(S, k0) do {                                                         \
    rAh##S = *(const bf16x8*)&Ah[aoff + (k0)];                                    \
    if constexpr (SPLIT) rAl##S = *(const bf16x8*)&Al[aoff + (k0)];               \
    if constexpr (B_F32) {                                                        \
        const float* Bf_ = (const float*)Bhp + bz * sB;                           \
        rBa##S = *(const float4*)&Bf_[boff + (k0)];                               \
        rBb##S = *(const float4*)&Bf_[boff + (k0) + 4];                           \
    } else {                                                                      \
        const __bf16* Bh_ = (const __bf16*)Bhp + bz * sB;                         \
        rBh##S = *(const bf16x8*)&Bh_[boff + (k0)];                               \
        if constexpr (SPLIT) {                                                    \
            const __bf16* Bl_ = (const __bf16*)Blp + bz * sB;                     \
            rBl##S = *(const bf16x8*)&Bl_[boff + (k0)];                           \
        }                                                                         \
    } } while (0)

#define WRITEL(S, buf) do {                                                       \
    *(bf16x8*)&sAh[buf][soff] = rAh##S;                                           \
    if constexpr (SPLIT) *(bf16x8*)&sAl[buf][soff] = rAl##S;                      \
    if constexpr (B_F32) {                                                        \
        bf16x8 h8_, l8_;                                                          \
        h8_[0] = (__bf16)rBa##S.x; l8_[0] = (__bf16)(rBa##S.x - (float)h8_[0]);   \
        h8_[1] = (__bf16)rBa##S.y; l8_[1] = (__bf16)(rBa##S.y - (float)h8_[1]);   \
        h8_[2] = (__bf16)rBa##S.z; l8_[2] = (__bf16)(rBa##S.z - (float)h8_[2]);   \
        h8_[3] = (__bf16)rBa##S.w; l8_[3] = (__bf16)(rBa##S.w - (float)h8_[3]);   \
        h8_[4] = (__bf16)rBb##S.x; l8_[4] = (__bf16)(rBb##S.x - (float)h8_[4]);   \
        h8_[5] = (__bf16)rBb##S.y; l8_[5] = (__bf16)(rBb##S.y - (float)h8_[5]);   \
        h8_[6] = (__bf16)rBb##S.z; l8_[6] = (__bf16)(rBb##S.z - (float)h8_[6]);   \
        h8_[7] = (__bf16)rBb##S.w; l8_[7] = (__bf16)(rBb##S.w - (float)h8_[7]);   \
        *(bf16x8*)&sBh[buf][soff] = h8_;                                          \
        *(bf16x8*)&sBl[buf][soff] = l8_;                                          \
    } else {                                                                      \
        *(bf16x8*)&sBh[buf][soff] = rBh##S;                                       \
        if constexpr (SPLIT) *(bf16x8*)&sBl[buf][soff] = rBl##S;                  \
    } } while (0)

    f32x4 acc[4][2];
#pragma unroll
    for (int i = 0; i < 4; ++i)
#pragma unroll
        for (int j = 0; j < 2; ++j) acc[i][j] = (f32x4)(0.f);

    auto DOMFMA = [&](int buf) {
        bf16x8 fbh[2], fbl[2];
#pragma unroll
        for (int j = 0; j < 2; ++j) {
            fbh[j] = *(const bf16x8*)&sBh[buf][bbase + j * 512];
            if constexpr (SPLIT)
                fbl[j] = *(const bf16x8*)&sBl[buf][bbase + j * 512];
        }
#pragma unroll
        for (int i = 0; i < 4; ++i) {
            bf16x8 fah = *(const bf16x8*)&sAh[buf][abase + i * 512];
            if constexpr (SPLIT) {
                bf16x8 fal = *(const bf16x8*)&sAl[buf][abase + i * 512];
#pragma unroll
                for (int j = 0; j < 2; ++j) {
                    acc[i][j] = __builtin_amdgcn_mfma_f32_16x16x32_bf16(fal, fbh[j], acc[i][j], 0, 0, 0);
                    acc[i][j] = __builtin_amdgcn_mfma_f32_16x16x32_bf16(fah, fbl[j], acc[i][j], 0, 0, 0);
                    acc[i][j] = __builtin_amdgcn_mfma_f32_16x16x32_bf16(fah, fbh[j], acc[i][j], 0, 0, 0);
                }
            } else {
#pragma unroll
                for (int j = 0; j < 2; ++j)
                    acc[i][j] = __builtin_amdgcn_mfma_f32_16x16x32_bf16(fah, fbh[j], acc[i][j], 0, 0, 0);
            }
        }
    };

    const int nt = K >> 5;                 // all uses: nt == 8
    LOADR(0, 0);
    if (nt > 1) LOADR(1, 32);
    WRITEL(0, 0);
    if (nt > 2) LOADR(0, 64);              // tile 2 -> set0 (regs freed by WRITEL)
    __syncthreads();

    for (int t = 0; t < nt; t += 2) {
        // ---- even step: compute tile t from lds0 ----
        DOMFMA(0);
        if (t + 1 < nt) {
            WRITEL(1, 1);                              // tile t+1 (loaded >=1.5 iters ago)
            if (t + 3 < nt) LOADR(1, (t + 3) << 5);    // tile t+3 -> set1
            __syncthreads();
            // ---- odd step: compute tile t+1 from lds1 ----
            DOMFMA(1);
            if (t + 2 < nt) {
                WRITEL(0, 0);                          // tile t+2
                if (t + 4 < nt) LOADR(0, (t + 4) << 5); // tile t+4 -> set0
                __syncthreads();
            }
        }
    }
#undef LOADR
#undef WRITEL

    // ---- epilogue: C[row][col], col = lane&15, row = quad*4 + r (m89-verified) ----
#pragma unroll
    for (int i = 0; i < 4; ++i)
#pragma unroll
        for (int j = 0; j < 2; ++j) {
            int col = n0 + wn + j * 16 + lr;
            int row0 = m0 + wm + i * 16 + quad * 4;
            float bv = bias ? bias[col] : 0.f;
#pragma unroll
            for (int r = 0; r < 4; ++r) {
                float v = acc[i][j][r] + bv;
                long long off = (long long)(row0 + r) * ldc + col + bz * sC;
                if constexpr (OUT_SPLIT) {
                    __bf16 h = (__bf16)v;
                    Chi[off] = h;
                    Clo[off] = (__bf16)(v - (float)h);
                } else {
                    Cf[off] = v;
                }
            }
        }
}

// ---------------- fp32 tiled GEMM (small/fold/residual gemms) -------------------
#define GTS 64
#define GKT 16
#define GPAD 68

template<int TRANSB, int RELU, int TRANSC>
__global__ __launch_bounds__(256) void gemm_f32(
    const float* __restrict__ A, int lda, long long sA,
    const float* __restrict__ Bm, int ldb, long long sB,
    const float* __restrict__ bias,
    float* __restrict__ C, int ldc, long long sC,
    int M, int N, int K)
{
    __shared__ float As[GKT][GPAD];
    __shared__ float Bs[GKT][GPAD];
    const int tid = threadIdx.x;
    const int tx = tid & 15, ty = tid >> 4;
    const int n0 = blockIdx.x * GTS;
    const int m0 = blockIdx.y * GTS;
    const long long bz = blockIdx.z;
    const float* Ab = A + bz * sA;
    const float* Bb = Bm + bz * sB;
    float* Cb = C + bz * sC;

    const int lr = tid >> 2;
    const int lc = (tid & 3) << 2;
    const int br = tid >> 4;
    const int bc = (tid & 15) << 2;

    float acc[4][4] = {};

    for (int k0 = 0; k0 < K; k0 += GKT) {
        float4 a = *(const float4*)&Ab[(long long)(m0 + lr) * lda + k0 + lc];
        As[lc + 0][lr] = a.x; As[lc + 1][lr] = a.y;
        As[lc + 2][lr] = a.z; As[lc + 3][lr] = a.w;
        if (TRANSB) {
            float4 b = *(const float4*)&Bb[(long long)(n0 + lr) * ldb + k0 + lc];
            Bs[lc + 0][lr] = b.x; Bs[lc + 1][lr] = b.y;
            Bs[lc + 2][lr] = b.z; Bs[lc + 3][lr] = b.w;
        } else {
            float4 b = *(const float4*)&Bb[(long long)(k0 + br) * ldb + n0 + bc];
            *(float4*)&Bs[br][bc] = b;
        }
        __syncthreads();
#pragma unroll
        for (int k = 0; k < GKT; ++k) {
            float4 av = *(const float4*)&As[k][ty << 2];
            float4 bv = *(const float4*)&Bs[k][tx << 2];
            float ar[4] = {av.x, av.y, av.z, av.w};
            float brr[4] = {bv.x, bv.y, bv.z, bv.w};
#pragma unroll
            for (int i = 0; i < 4; ++i)
#pragma unroll
                for (int j = 0; j < 4; ++j)
                    acc[i][j] = fmaf(ar[i], brr[j], acc[i][j]);
        }
        __syncthreads();
    }

    float bbr[4] = {0.f, 0.f, 0.f, 0.f};
    if (bias) {
        float4 bb = *(const float4*)&bias[n0 + (tx << 2)];
        bbr[0] = bb.x; bbr[1] = bb.y; bbr[2] = bb.z; bbr[3] = bb.w;
    }
#pragma unroll
    for (int i = 0; i < 4; ++i) {
#pragma unroll
        for (int j = 0; j < 4; ++j) {
            float o = acc[i][j] + bbr[j];
            if (RELU) o = fmaxf(o, 0.f);
            if (TRANSC)
                Cb[(long long)(n0 + (tx << 2) + j) * ldc + m0 + (ty << 2) + i] = o;
            else
                Cb[(long long)(m0 + (ty << 2) + i) * ldc + n0 + (tx << 2) + j] = o;
        }
    }
}

// ---------------- word_pe: scan + table + streaming add/split -------------------
// pe depends only on (count, c); count = cumsum(mask) is an integer in [0,256]
// -> precompute a 257x256 table (bit-identical powf/sinf/cosf), then stream.

__global__ __launch_bounds__(256) void cumsum_kernel(
    const int* __restrict__ tm, int* __restrict__ cums)
{
    int b = blockIdx.x, c = threadIdx.x;
    int lane = c & 63;
    int v = (tm[(long long)b * LFULL + 1 + c] != 0) ? 1 : 0;
#pragma unroll
    for (int off = 1; off < 64; off <<= 1) {
        int t = __shfl_up(v, off);
        if (lane >= off) v += t;
    }
    __shared__ int wsum[4];
    if (lane == 63) wsum[c >> 6] = v;
    __syncthreads();
    int w = c >> 6, add = 0;
    for (int i = 0; i < w; ++i) add += wsum[i];
    cums[b * LW + c] = v + add;
}

__global__ __launch_bounds__(256) void pe_table_kernel(float* __restrict__ petab)
{
    int n = blockIdx.x;          // count value 0..256
    int c = threadIdx.x;
    int i2 = c & ~1;
    float freq = powf(10000.0f, (float)i2 / (float)CC);
    float arg = (float)n / freq;
    petab[n * CC + c] = (c & 1) ? cosf(arg) : sinf(arg);
}

__global__ __launch_bounds__(256) void word_pe2_kernel(
    const float* __restrict__ te, const int* __restrict__ cums,
    const float* __restrict__ petab,
    __bf16* __restrict__ whi, __bf16* __restrict__ wlo)
{
    int g = blockIdx.x * 256 + threadIdx.x;   // 0 .. 128*256*64-1
    int c0 = (g & 63) << 2;                   // channel base (float4)
    int l  = (g >> 6) & 255;
    int b  = g >> 14;
    int cnt = cums[b * LW + l];
    float4 s = *(const float4*)&te[((long long)(b * LFULL + 1 + l)) * CC + c0];
    float4 p = *(const float4*)&petab[cnt * CC + c0];
    float v0 = s.x + p.x, v1 = s.y + p.y, v2 = s.z + p.z, v3 = s.w + p.w;
    bf16x4 h, lo;
    h[0] = (__bf16)v0; lo[0] = (__bf16)(v0 - (float)h[0]);
    h[1] = (__bf16)v1; lo[1] = (__bf16)(v1 - (float)h[1]);
    h[2] = (__bf16)v2; lo[2] = (__bf16)(v2 - (float)h[2]);
    h[3] = (__bf16)v3; lo[3] = (__bf16)(v3 - (float)h[3]);
    long long o = ((long long)(b * LW + l)) * CC + c0;
    *(bf16x4*)&whi[o] = h;
    *(bf16x4*)&wlo[o] = lo;
}

// ---------------- weight prep -------------------------------------------------
__global__ __launch_bounds__(256) void split_transpose_kernel(
    const float* __restrict__ W, __bf16* __restrict__ hi, __bf16* __restrict__ lo)
{
    int n = blockIdx.x, k = threadIdx.x;
    float v = W[(long long)k * CC + n];
    __bf16 h = (__bf16)v;
    hi[(long long)n * CC + k] = h;
    lo[(long long)n * CC + k] = (__bf16)(v - (float)h);
}
__global__ __launch_bounds__(256) void split_plain_kernel(
    const float* __restrict__ W, __bf16* __restrict__ hi, __bf16* __restrict__ lo)
{
    int g = blockIdx.x * 256 + threadIdx.x;
    float v = W[g];
    __bf16 h = (__bf16)v;
    hi[g] = h;
    lo[g] = (__bf16)(v - (float)h);
}
__global__ __launch_bounds__(256) void cvt_bf16_kernel(
    const float* __restrict__ src, __bf16* __restrict__ dst)
{
    int g = blockIdx.x * 256 + threadIdx.x;
    dst[g] = (__bf16)src[g];
}

// ---------------- in-place softmax over T + entropy ----------------------------
__global__ __launch_bounds__(256) void softmax_entropy_kernel(
    float* __restrict__ attn, const int* __restrict__ vmask,
    float* __restrict__ ent)
{
    __shared__ float lds[4];
    long long row = blockIdx.x;
    int b = blockIdx.x >> 8;
    float* p = attn + row * TT;
    const int* m = vmask + (long long)b * TT;
    int t4 = threadIdx.x * 4;
    float4 v = *(const float4*)&p[t4];
    int4 mm4 = *(const int4*)&m[t4];
    float x[4];
    x[0] = mm4.x ? v.x : -INFINITY;
    x[1] = mm4.y ? v.y : -INFINITY;
    x[2] = mm4.z ? v.z : -INFINITY;
    x[3] = mm4.w ? v.w : -INFINITY;
    float mx = fmaxf(fmaxf(x[0], x[1]), fmaxf(x[2], x[3]));
    mx = blockReduceMax(mx, lds);
    float e[4];
    float ps = 0.f;
#pragma unroll
    for (int j = 0; j < 4; ++j) { e[j] = expf(x[j] - mx); ps += e[j]; }
    float sum = blockReduceSum(ps, lds);
    float q[4];
    float ce = 0.f;
#pragma unroll
    for (int j = 0; j < 4; ++j) {
        q[j] = e[j] / sum;
        ce += q[j] * logf(q[j] + 1e-6f);
    }
    ce = blockReduceSum(ce, lds);
    *(float4*)&p[t4] = make_float4(q[0], q[1], q[2], q[3]);
    if (threadIdx.x == 0) ent[row] = -ce;
}

// ---------------- greedy selection ---------------------------------------------
__global__ __launch_bounds__(256) void select_kernel(
    const float* __restrict__ ent, const int* __restrict__ tm,
    int* __restrict__ sel)
{
    int b = blockIdx.x;
    int l = threadIdx.x;
    __shared__ float sc[LW];
    __shared__ int ord[LW];
    __shared__ unsigned char mk[LW];
    mk[l] = (tm[(long long)b * LFULL + 1 + l] != 0);
    sc[l] = mk[l] ? ent[(long long)b * LW + l] : -INFINITY;
    __syncthreads();
    float mys = sc[l];
    int r = 0;
    for (int j = 0; j < LW; ++j) {
        float s = sc[j];
        r += (s > mys) || (s == mys && j < l);
    }
    ord[r] = l;
    __syncthreads();
    if (l == 0) {
        int chosen[PP];
        int cnt = 0;
        for (int t = 0; t < LW; ++t) {
            int idx = ord[t];
            if (!mk[idx]) continue;
            if (cnt >= PP) break;
            bool ok = true;
            for (int s2 = 0; s2 < cnt; ++s2) {
                int d = idx - chosen[s2];
                if (d < 0) d = -d;
                if (d < 2) ok = false;
            }
            if (ok) chosen[cnt++] = idx;
        }
        int last = (cnt > 0) ? chosen[cnt - 1] : -1;
        for (int p = 0; p < PP; ++p)
            sel[b * PP + p] = (p < cnt) ? chosen[p] : last;
    }
}

// ---------------- gather selected rows of word_pe (hi+lo) ----------------------
__global__ __launch_bounds__(256) void gather_kernel(
    const __bf16* __restrict__ whi, const __bf16* __restrict__ wlo,
    const int* __restrict__ sel, float* __restrict__ x0)
{
    int g = blockIdx.x * 256 + threadIdx.x;
    int b = g >> 11;
    int p = (g >> 8) & 7;
    int c = g & 255;
    int idx = sel[b * PP + p];
    if (idx < 0) idx = 0;
    long long off = ((long long)b * LW + idx) * CC + c;
    x0[g] = (float)whi[off] + (float)wlo[off];
}

// ---------------- effective biases ---------------------------------------------
__global__ __launch_bounds__(256) void eff_bias_kernel(
    const float* __restrict__ q_b, const float* __restrict__ kv_b,
    const float* __restrict__ in_w, const float* __restrict__ in_b,
    float* __restrict__ BQE_all, float* __restrict__ bkv3)
{
    int i = blockIdx.x / 3;
    int role = blockIdx.x % 3;
    int n = threadIdx.x;
    const float* inw = in_w + (long long)i * 196608;
    const float* inb = in_b + (long long)i * 768;
    const float* srcb;
    int co;
    float* dst;
    if (role == 0)      { srcb = q_b + i * 256;        co = 0;   dst = BQE_all + i * 256; }
    else if (role == 1) { srcb = kv_b + i * 512;       co = 256; dst = bkv3 + i * 512; }
    else                { srcb = kv_b + i * 512 + 256; co = 512; dst = bkv3 + i * 512 + 256; }
    float s = inb[co + n];
#pragma unroll 8
    for (int k = 0; k < CC; ++k)
        s = fmaf(srcb[k], inw[(long long)k * 768 + co + n], s);
    dst[n] = s;
}

// ---------------- attention scores + softmax (block per (b,h)); KV ld=512 ------
__global__ __launch_bounds__(256) void attn_scores_kernel(
    const float* __restrict__ qp, const float* __restrict__ KV,
    const int* __restrict__ tm, float* __restrict__ attn)
{
    int b = blockIdx.x, h = blockIdx.y;
    int tid = threadIdx.x;
    __shared__ float qs[PP][DHD];
    __shared__ float sc[PP][LW];
    __shared__ float mxs[PP], sms[PP];
    {
        int q = tid >> 5, d = tid & 31;
        qs[q][d] = qp[((long long)(b * PP + q)) * CC + h * DHD + d];
    }
    __syncthreads();
    const float* kr = KV + ((long long)(b * LW + tid)) * 512 + h * DHD;
    float kreg[DHD];
#pragma unroll
    for (int j = 0; j < 8; ++j) {
        float4 f = *(const float4*)&kr[j * 4];
        kreg[j * 4 + 0] = f.x; kreg[j * 4 + 1] = f.y;
        kreg[j * 4 + 2] = f.z; kreg[j * 4 + 3] = f.w;
    }
    bool mk = tm[(long long)b * LFULL + 1 + tid] != 0;
#pragma unroll
    for (int q = 0; q < PP; ++q) {
        float s = 0.f;
#pragma unroll
        for (int d = 0; d < DHD; ++d) s = fmaf(qs[q][d], kreg[d], s);
        sc[q][tid] = mk ? s * 0.17677669529663687f : -INFINITY;
    }
    __syncthreads();
    {
        int q = tid >> 5, j = tid & 31;
        float m = -INFINITY;
        for (int kk = j; kk < LW; kk += 32) m = fmaxf(m, sc[q][kk]);
#pragma unroll
        for (int mm = 16; mm >= 1; mm >>= 1) m = fmaxf(m, __shfl_xor(m, mm, 32));
        float s = 0.f;
        for (int kk = j; kk < LW; kk += 32) s += expf(sc[q][kk] - m);
#pragma unroll
        for (int mm = 16; mm >= 1; mm >>= 1) s += __shfl_xor(s, mm, 32);
        if (j == 0) { mxs[q] = m; sms[q] = s; }
    }
    __syncthreads();
#pragma unroll
    for (int q = 0; q < PP; ++q) {
        float pv = expf(sc[q][tid] - mxs[q]) / sms[q];
        attn[(((long long)(b * NH + h)) * PP + q) * LW + tid] = pv;
    }
}

// ---------------- attn @ V (block per (b,q)); V at KV col offset 256 -----------
__global__ __launch_bounds__(256) void attn_out_kernel(
    const float* __restrict__ attn, const float* __restrict__ KV,
    float* __restrict__ aout)
{
    int b = blockIdx.x, q = blockIdx.y;
    int c = threadIdx.x, h = c >> 5;
    __shared__ float att[NH][LW];
#pragma unroll
    for (int hh = 0; hh < NH; ++hh)
        att[hh][c] = attn[(((long long)(b * NH + hh)) * PP + q) * LW + c];
    __syncthreads();
    const float* vpb = KV + ((long long)b * LW) * 512 + 256 + c;
    float acc = 0.f;
#pragma unroll 8
    for (int k = 0; k < LW; ++k)
        acc = fmaf(att[h][k], vpb[(long long)k * 512], acc);
    aout[((long long)(b * PP + q)) * CC + c] = acc;
}

// ---------------- slot_sim = mean over heads -----------------------------------
__global__ __launch_bounds__(256) void slot_sim_kernel(
    const float* __restrict__ attn, float* __restrict__ outs)
{
    int b = blockIdx.x, q = blockIdx.y, k = threadIdx.x;
    float s = 0.f;
#pragma unroll
    for (int h = 0; h < NH; ++h)
        s += attn[(((long long)(b * NH + h)) * PP + q) * LW + k];
    outs[((long long)(b * PP + q)) * LW + k] = s * 0.125f;
}

// ---------------- residual + layer norm ----------------------------------------
__global__ __launch_bounds__(256) void ln_residual_kernel(
    const float* __restrict__ xin, const float* __restrict__ add,
    const float* __restrict__ g, const float* __restrict__ bta,
    float* __restrict__ out)
{
    __shared__ float lds[4];
    int r = blockIdx.x, c = threadIdx.x;
    long long idx = (long long)r * CC + c;
    float v = xin[idx] + add[idx];
    float s = blockReduceSum(v, lds);
    float mu = s * (1.0f / (float)CC);
    float d = v - mu;
    float var = blockReduceSum(d * d, lds) * (1.0f / (float)CC);
    out[idx] = d / sqrtf(var + 1e-5f) * g[c] + bta[c];
}

// ---------------- eos broadcast -------------------------------------------------
__global__ __launch_bounds__(256) void eos_kernel(
    const float* __restrict__ eos, float* __restrict__ outp)
{
    outp[(long long)blockIdx.x * CC + threadIdx.x] = eos[threadIdx.x];
}

// =================================================================================
extern "C" void kernel_launch(void* const* d_in, const int* in_sizes, int n_in,
                              void* d_out, int out_size, void* d_ws, size_t ws_size,
                              hipStream_t stream) {
    const float* txt_emb     = (const float*)d_in[0];
    const int*   txt_mask    = (const int*)d_in[1];
    const float* video_feats = (const float*)d_in[2];
    const int*   video_mask  = (const int*)d_in[3];
    const float* word_proj_w = (const float*)d_in[4];
    const float* word_proj_b = (const float*)d_in[5];
    const float* video_proj_w = (const float*)d_in[6];
    // video_proj_b drops out (softmax shift invariance)
    const float* q_w   = (const float*)d_in[8];
    const float* q_b   = (const float*)d_in[9];
    const float* kv_w  = (const float*)d_in[10];
    const float* kv_b  = (const float*)d_in[11];
    const float* in_w  = (const float*)d_in[12];
    const float* in_b  = (const float*)d_in[13];
    const float* out_w = (const float*)d_in[14];
    const float* out_b = (const float*)d_in[15];
    const float* ln0_g = (const float*)d_in[16];
    const float* ln0_b = (const float*)d_in[17];
    const float* lin_w = (const float*)d_in[18];
    const float* lin_b = (const float*)d_in[19];
    const float* ln1_g = (const float*)d_in[20];
    const float* ln1_b = (const float*)d_in[21];
    const float* eos_slot = (const float*)d_in[22];

    // workspace layout (float units, ~120 MiB)
    float* ws = (float*)d_ws;
    __bf16* wpe_hi = (__bf16*)(ws + 0LL);          // 8388608 bf16
    __bf16* wpe_lo = (__bf16*)(ws + 4194304LL);    // 8388608 bf16
    __bf16* wp_hi  = (__bf16*)(ws + 8388608LL);
    __bf16* wp_lo  = (__bf16*)(ws + 12582912LL);
    __bf16* U_hi   = (__bf16*)(ws + 16777216LL);
    __bf16* U_lo   = (__bf16*)(ws + 20971520LL);
    float*  KV     = ws + 8388608LL;               // 32768x512 fp32 (overlaps wp/U)
    float* ent     = ws + 25165824LL;              // 32768
    int*   sel     = (int*)(ws + 25198592LL);      // 1024
    float* x0      = ws + 25199616LL;
    float* x1      = ws + 25461760LL;
    float* xmid    = ws + 25723904LL;
    float* qp      = ws + 25986048LL;
    float* attnw   = ws + 26248192LL;              // 2097152
    float* aout    = ws + 28345344LL;
    float* qatt    = ws + 28607488LL;
    float* upd     = ws + 28869632LL;
    float* WQE_all = ws + 29131776LL;              // 3*65536
    float* BQE_all = ws + 29328384LL;              // 768
    float* WT3f    = ws + 29329152LL;              // 393216 (3 layers x [512][256])
    __bf16* WT3    = (__bf16*)(ws + 29722368LL);   // 393216 bf16
    float* bkv3    = ws + 29918976LL;              // 1536
    __bf16* WPT_hi = (__bf16*)(ws + 29920512LL);   // 65536 bf16
    __bf16* WPT_lo = (__bf16*)(ws + 29953280LL);
    __bf16* VPS_hi = (__bf16*)(ws + 29986048LL);
    __bf16* VPS_lo = (__bf16*)(ws + 30018816LL);

    // transient (dead before step 3 writes the wp_hi/KV region): cums + pe table
    int*   cums  = (int*)(ws + 8388608LL);         // 32768 ints
    float* petab = ws + 8421376LL;                 // 257*256 floats

    float* outp     = (float*)d_out;
    float* out_ps   = outp;
    float* out_attn = outp + 262144LL;
    float* out_slot = outp + 33816576LL;
    float* out_eos  = outp + 34078720LL;

    // 1. word_pe (split bf16): scan + table + streaming add/split
    cumsum_kernel<<<dim3(BB), dim3(256), 0, stream>>>(txt_mask, cums);
    pe_table_kernel<<<dim3(257), dim3(256), 0, stream>>>(petab);
    word_pe2_kernel<<<dim3(8192), dim3(256), 0, stream>>>(txt_emb, cums, petab, wpe_hi, wpe_lo);
    // 2. weight preps
    split_transpose_kernel<<<dim3(256), dim3(256), 0, stream>>>(word_proj_w, WPT_hi, WPT_lo);
    split_plain_kernel<<<dim3(256), dim3(256), 0, stream>>>(video_proj_w, VPS_hi, VPS_lo);
    // 3. wp = word_pe @ Wword + b   (split x split -> split out)
    gemm_mfma<1,0,1><<<dim3(2,256,1), dim3(512), 0, stream>>>(
        wpe_hi, wpe_lo, 256, 0, WPT_hi, WPT_lo, 256, 0, word_proj_b,
        nullptr, wp_hi, wp_lo, 256, 0, 32768, 256, 256);
    // 4. U = wp @ Wvid^T            (split x split -> split out)
    gemm_mfma<1,0,1><<<dim3(2,256,1), dim3(512), 0, stream>>>(
        wp_hi, wp_lo, 256, 0, VPS_hi, VPS_lo, 256, 0, nullptr,
        nullptr, U_hi, U_lo, 256, 0, 32768, 256, 256);
    // 5. sim = U[b] @ video[b]^T    (split x fp32-in-kernel -> fp32 out_attn)
    gemm_mfma<1,1,0><<<dim3(8,2,BB), dim3(512), 0, stream>>>(
        U_hi, U_lo, 256, 65536LL, video_feats, nullptr, 256, 262144LL, nullptr,
        out_attn, nullptr, nullptr, 1024, 262144LL, 256, 1024, 256);
    // 6. softmax + entropy (in place)
    softmax_entropy_kernel<<<dim3(32768), dim3(256), 0, stream>>>(out_attn, video_mask, ent);
    // 7. selection + gather
    select_kernel<<<dim3(BB), dim3(256), 0, stream>>>(ent, txt_mask, sel);
    gather_kernel<<<dim3(1024), dim3(256), 0, stream>>>(wpe_hi, wpe_lo, sel, x0);

    // 8. folded weights (all layers, z-batched)
    gemm_f32<0,0,0><<<dim3(4,4,3), dim3(256), 0, stream>>>(
        q_w,256,65536LL, in_w,768,196608LL, nullptr, WQE_all,256,65536LL, 256,256,256);
    gemm_f32<0,0,1><<<dim3(4,4,3), dim3(256), 0, stream>>>(
        kv_w,512,131072LL, in_w+256,768,196608LL, nullptr, WT3f,256,131072LL, 256,256,256);
    gemm_f32<0,0,1><<<dim3(4,4,3), dim3(256), 0, stream>>>(
        kv_w+256,512,131072LL, in_w+512,768,196608LL, nullptr, WT3f+65536,256,131072LL, 256,256,256);
    eff_bias_kernel<<<dim3(9), dim3(256), 0, stream>>>(q_b, kv_b, in_w, in_b, BQE_all, bkv3);
    cvt_bf16_kernel<<<dim3(1536), dim3(256), 0, stream>>>(WT3f, (__bf16*)WT3);

    float* X = x0;
    for (int i = 0; i < NLAY; ++i) {
        const float* ow  = out_w + (long long)i * 65536;
        const float* ob  = out_b + (long long)i * 256;
        const float* g0  = ln0_g + (long long)i * 256;
        const float* b0  = ln0_b + (long long)i * 256;
        const float* lw  = lin_w + (long long)i * 65536;
        const float* lb  = lin_b + (long long)i * 256;
        const float* g1  = ln1_g + (long long)i * 256;
        const float* b1  = ln1_b + (long long)i * 256;

        gemm_mfma<0,0,0><<<dim3(4,256,1), dim3(512), 0, stream>>>(
            wpe_hi, nullptr, 256, 0, WT3 + (long long)i * 131072, nullptr, 256, 0,
            bkv3 + i * 512, KV, nullptr, nullptr, 512, 0, 32768, 512, 256);

        gemm_f32<0,0,0><<<dim3(4,16,1), dim3(256), 0, stream>>>(
            X,256,0, WQE_all + (long long)i*65536,256,0, BQE_all + i*256, qp,256,0, 1024,256,256);

        attn_scores_kernel<<<dim3(BB,NH), dim3(256), 0, stream>>>(qp, KV, txt_mask, attnw);
        attn_out_kernel<<<dim3(BB,PP), dim3(256), 0, stream>>>(attnw, KV, aout);
        if (i == NLAY - 1)
            slot_sim_kernel<<<dim3(BB,PP), dim3(256), 0, stream>>>(attnw, out_slot);

        gemm_f32<0,0,0><<<dim3(4,16,1), dim3(256), 0, stream>>>(
            aout,256,0, ow,256,0, ob, qatt,256,0, 1024,256,256);
        ln_residual_kernel<<<dim3(1024), dim3(256), 0, stream>>>(X, qatt, g0, b0, xmid);
        gemm_f32<0,1,0><<<dim3(4,16,1), dim3(256), 0, stream>>>(
            xmid,256,0, lw,256,0, lb, upd,256,0, 1024,256,256);
        float* Xout = (i == NLAY - 1) ? out_ps : ((X == x0) ? x1 : x0);
        ln_residual_kernel<<<dim3(1024), dim3(256), 0, stream>>>(xmid, upd, g1, b1, Xout);
        X = Xout;
    }
    eos_kernel<<<dim3(BB), dim3(256), 0, stream>>>(eos_slot, out_eos);
}